// Round 7
// baseline (223.000 us; speedup 1.0000x reference)
//
#include <hip/hip_runtime.h>
#include <hip/hip_bf16.h>
#include <cstdint>
#include <cstddef>

// MXAttention: B=4, S=1024, E=1024, H=16, D=64. fp32 in/out.
// MX quant: blocks of 32 along last/contraction dim, scale=2^(floor(log2(amax))-8),
// e4m3 grid == OCP e4m3fn. qdq = pre-clamp to +-448 then HW v_cvt_pk_fp8_f32 /
// v_cvt_f32_fp8 (RNE). Pre-clamp+convert == reference round-then-clip.
//
// GEMMs: quantized operands are e4m3 x pow2 => exactly bf16 => bf16 MFMA, fp32 acc.
// Q/K/V GEMM epilogues emit results pre-split into bf16 hi+lo planes (Q pre-scaled
// by 0.125, exact); attention uses 3 cross-term MFMAs (lo*lo dropped, ~2^-16).
// V planes stored transposed (Vt[b,h,d,s]). K/V staged via global_load_lds.
//
// gemm_qkv (this revision): z-merged (one WG computes the same 128x128 m,n tile
// for Q,K,V sharing one A stage) + BK=32 with FOUR LDS buffers (128KB) and
// 3-DEEP prefetch: at 1 WG/CU there is no other WG to hide load latency, so
// loads get ~3 K-steps (~1000cy) to land (A-panels are cold HBM ~900cy).
// Store/read XOR swizzle pair is the R3/R4-verified BK=32 one.
//
// attn (this revision): skewed QK/PV pipeline — phase t computes QK(t) and
// PV(t-1) back-to-back (independent MFMA streams), then softmax(t). o-sequence
// becomes {o += P(t-1)V(t-1); o *= alpha(t)} == bit-identical to the serial
// form. V staging lags K by one tile; extra epilogue window stages V(15).
//
// ws layout (bytes):
//   [ 0, 8)MB  XQb  bf16 quantized input; later reused as CTXQb
//   [ 8,16)MB  WQb/WKb/WVb/WOb (2 MB each)
//   [16,24) Qhi [24,32) Qlo   [32,40) Khi [40,48) Klo   [48,56) Vthi [56,64) Vtlo

#define S_LEN 1024
#define E_DIM 1024
#define NH    16
#define DH    64
#define BATCH 4
#define NROWS (BATCH * S_LEN)  // 4096

typedef short          bf16x8  __attribute__((ext_vector_type(8)));
typedef float          f32x4   __attribute__((ext_vector_type(4)));
typedef unsigned short u16x8   __attribute__((ext_vector_type(8)));
typedef unsigned short u16x4   __attribute__((ext_vector_type(4)));
typedef unsigned int   u32x4   __attribute__((ext_vector_type(4)));

// ---------------- MX quant helpers ----------------

// scale = 2^(clamp(floor(log2(amax))-8, -126, 126)), 1.0 if amax==0.
__device__ __forceinline__ void mx_scale_bits(float amax, float& scale, float& inv) {
  int eb = (int)(__float_as_uint(amax) >> 23);  // biased exponent
  int sb = eb - 8;
  sb = sb < 1 ? 1 : (sb > 253 ? 253 : sb);
  float sc = __uint_as_float((unsigned)sb << 23);
  float iv = __uint_as_float((unsigned)(254 - sb) << 23);
  bool nz = (amax > 0.0f);
  scale = nz ? sc : 1.0f;
  inv   = nz ? iv : 1.0f;
}

// round a,b to the e4m3fn grid: pre-clamp +-448 (== ref round-then-clip), HW RNE cvt.
__device__ __forceinline__ void qdq2(float& a, float& b) {
  a = fminf(fmaxf(a, -448.0f), 448.0f);
  b = fminf(fmaxf(b, -448.0f), 448.0f);
  int p = __builtin_amdgcn_cvt_pk_fp8_f32(a, b, 0, false);
  a = __builtin_amdgcn_cvt_f32_fp8(p, 0);
  b = __builtin_amdgcn_cvt_f32_fp8(p, 1);
}

__device__ __forceinline__ unsigned short f32_to_bf16_rne(float f) {
  unsigned u = __float_as_uint(f);
  unsigned r = 0x7FFFu + ((u >> 16) & 1u);
  return (unsigned short)((u + r) >> 16);
}

// ---- cross-quad (lanes ^16, ^32) all-reduce via gfx950 permlane swaps ----
__device__ __forceinline__ float quad_red_max(float x) {
  auto p = __builtin_amdgcn_permlane16_swap(__float_as_uint(x), __float_as_uint(x), false, false);
  x = fmaxf(__uint_as_float(p[0]), __uint_as_float(p[1]));
  auto q = __builtin_amdgcn_permlane32_swap(__float_as_uint(x), __float_as_uint(x), false, false);
  return fmaxf(__uint_as_float(q[0]), __uint_as_float(q[1]));
}
__device__ __forceinline__ float quad_red_min(float x) {
  auto p = __builtin_amdgcn_permlane16_swap(__float_as_uint(x), __float_as_uint(x), false, false);
  x = fminf(__uint_as_float(p[0]), __uint_as_float(p[1]));
  auto q = __builtin_amdgcn_permlane32_swap(__float_as_uint(x), __float_as_uint(x), false, false);
  return fminf(__uint_as_float(q[0]), __uint_as_float(q[1]));
}
__device__ __forceinline__ float quad_red_sum(float x) {
  auto p = __builtin_amdgcn_permlane16_swap(__float_as_uint(x), __float_as_uint(x), false, false);
  x = __uint_as_float(p[0]) + __uint_as_float(p[1]);
  auto q = __builtin_amdgcn_permlane32_swap(__float_as_uint(x), __float_as_uint(x), false, false);
  return __uint_as_float(q[0]) + __uint_as_float(q[1]);
}

// ---------------- quant kernel: fp32 in -> bf16 out (exact) ----------------

__device__ __forceinline__ void mxq_body(const float* __restrict__ in,
                                         unsigned short* __restrict__ out, int b) {
  const float4* p = (const float4*)(in + (size_t)b * 32);
  float v[32];
#pragma unroll
  for (int g = 0; g < 8; ++g) {
    float4 t = p[g];
    v[g * 4 + 0] = t.x; v[g * 4 + 1] = t.y; v[g * 4 + 2] = t.z; v[g * 4 + 3] = t.w;
  }
  float amax = 0.0f;
#pragma unroll
  for (int i = 0; i < 32; ++i) amax = fmaxf(amax, __builtin_fabsf(v[i]));
  float scale, inv;
  mx_scale_bits(amax, scale, inv);
  u16x8* q = (u16x8*)(out + (size_t)b * 32);
#pragma unroll
  for (int g = 0; g < 4; ++g) {
    u16x8 o;
#pragma unroll
    for (int e = 0; e < 8; e += 2) {
      float a = v[g * 8 + e] * inv, c = v[g * 8 + e + 1] * inv;
      qdq2(a, c);
      o[e]     = (unsigned short)(__float_as_uint(a * scale) >> 16);  // exact bf16
      o[e + 1] = (unsigned short)(__float_as_uint(c * scale) >> 16);
    }
    q[g] = o;
  }
}

// one launch quantizes x (blocks 0..511) + 4 weights (128 blocks each)
__global__ __launch_bounds__(256)
void mxq_all(const float* __restrict__ x,
             const float* __restrict__ w0, const float* __restrict__ w1,
             const float* __restrict__ w2, const float* __restrict__ w3,
             unsigned short* __restrict__ ox,
             unsigned short* __restrict__ o0, unsigned short* __restrict__ o1,
             unsigned short* __restrict__ o2, unsigned short* __restrict__ o3) {
  int blk = blockIdx.x;
  const float* in;
  unsigned short* out;
  int base;
  if (blk < 512)      { in = x;  out = ox; base = blk; }
  else if (blk < 640) { in = w0; out = o0; base = blk - 512; }
  else if (blk < 768) { in = w1; out = o1; base = blk - 640; }
  else if (blk < 896) { in = w2; out = o2; base = blk - 768; }
  else                { in = w3; out = o3; base = blk - 896; }
  mxq_body(in, out, base * 256 + threadIdx.x);
}

// ---------------- Z-merged Q/K/V bf16 MFMA NT GEMM (BK=32, 4-buffer) ----------
// 512 threads / 8 waves. Tile 128x128 shared across z=Q,K,V. BK=32, 4 bufs,
// 3-deep prefetch, vmcnt(12) counted pipeline. LDS 128KB, 1 WG/CU, grid 256.
// Wave w: rows wm=(w&3)*32, cols wn=(w>>2)*64. acc[3][2][4].
// Staging: 4 gload_lds/lane/K-step; each wave stages its 16 rows per matrix.

__global__ __launch_bounds__(512, 2)
void gemm_qkv(const unsigned short* __restrict__ XQ,
              const unsigned short* __restrict__ Wqw, const unsigned short* __restrict__ Wkw,
              const unsigned short* __restrict__ Wvw,
              const float* __restrict__ bq, const float* __restrict__ bk,
              const float* __restrict__ bv,
              unsigned short* __restrict__ Qhi, unsigned short* __restrict__ Qlo,
              unsigned short* __restrict__ Khi, unsigned short* __restrict__ Klo,
              unsigned short* __restrict__ Vthi, unsigned short* __restrict__ Vtlo) {
  __shared__ unsigned short sA [4][128 * 32];
  __shared__ unsigned short sBq[4][128 * 32];
  __shared__ unsigned short sBk[4][128 * 32];
  __shared__ unsigned short sBv[4][128 * 32];
  const int tid = threadIdx.x;
  const int w = tid >> 6, ln = tid & 63;
  // XCD-bijective swizzle over the (8,32) grid: each XCD owns 4 M-bands x 8 N.
  const int fid = blockIdx.y * 8 + blockIdx.x;
  const int xcd = fid & 7, sq = fid >> 3;
  const int bm = (xcd * 4 + (sq & 3)) * 128, bn = (sq >> 2) * 128;
  const int wm = (w & 3) * 32, wn = (w >> 2) * 64;
  const int quad = ln >> 4, col = ln & 15;

  f32x4 acc[3][2][4];
  f32x4 zero = {0.0f, 0.0f, 0.0f, 0.0f};
#pragma unroll
  for (int z = 0; z < 3; ++z)
#pragma unroll
    for (int i = 0; i < 2; ++i)
#pragma unroll
      for (int j = 0; j < 4; ++j) acc[z][i][j] = zero;

  // staging geometry (BK=32): wave stages rows [w*16, w*16+16), 4x16B chunks/row.
  // lane ln -> row w*16 + (ln>>2), LDS pos ln&3; global chunk cc = pos ^ ((row>>1)&3).
  const int srow = (w << 4) + (ln >> 2);          // 0..127
  const int cc   = (ln & 3) ^ ((srow >> 1) & 3);
  const int dsto = w * 512;                        // shorts: wave-uniform LDS base
  // read: global chunk quad of row base16+col at pos quad ^ ((col>>1)&3)
  const int xoq = ((quad ^ (col >> 1)) & 3) * 8;

  auto STAGE = [&](int bb, int k0) {
    const size_t goffA = (size_t)(bm + srow) * 1024 + k0 + cc * 8;
    const size_t goffB = (size_t)(bn + srow) * 1024 + k0 + cc * 8;
    __builtin_amdgcn_global_load_lds(
        (const __attribute__((address_space(1))) unsigned int*)(XQ + goffA),
        (__attribute__((address_space(3))) unsigned int*)(&sA[bb][0] + dsto),
        16, 0, 0);
    __builtin_amdgcn_global_load_lds(
        (const __attribute__((address_space(1))) unsigned int*)(Wqw + goffB),
        (__attribute__((address_space(3))) unsigned int*)(&sBq[bb][0] + dsto),
        16, 0, 0);
    __builtin_amdgcn_global_load_lds(
        (const __attribute__((address_space(1))) unsigned int*)(Wkw + goffB),
        (__attribute__((address_space(3))) unsigned int*)(&sBk[bb][0] + dsto),
        16, 0, 0);
    __builtin_amdgcn_global_load_lds(
        (const __attribute__((address_space(1))) unsigned int*)(Wvw + goffB),
        (__attribute__((address_space(3))) unsigned int*)(&sBv[bb][0] + dsto),
        16, 0, 0);
  };

  STAGE(0, 0);
  STAGE(1, 32);
  STAGE(2, 64);
#pragma unroll 1
  for (int it = 0; it < 32; ++it) {
    const int cur = it & 3;
    if (it < 29) {
      STAGE((it + 3) & 3, (it + 3) * 32);
      asm volatile("s_waitcnt vmcnt(12)" ::: "memory");  // tile it's 4 loads done
    } else if (it == 29) {
      asm volatile("s_waitcnt vmcnt(8)" ::: "memory");
    } else if (it == 30) {
      asm volatile("s_waitcnt vmcnt(4)" ::: "memory");
    } else {
      asm volatile("s_waitcnt vmcnt(0)" ::: "memory");
    }
    __builtin_amdgcn_s_barrier();          // cur fully staged & visible to all waves
    __builtin_amdgcn_sched_barrier(0);

    bf16x8 af[2];
#pragma unroll
    for (int t = 0; t < 2; ++t)
      af[t] = *(const bf16x8*)(&sA[cur][0] + (wm + t * 16 + col) * 32 + xoq);
    {
      bf16x8 bfr[4];
#pragma unroll
      for (int t = 0; t < 4; ++t)
        bfr[t] = *(const bf16x8*)(&sBq[cur][0] + (wn + t * 16 + col) * 32 + xoq);
#pragma unroll
      for (int ti = 0; ti < 2; ++ti)
#pragma unroll
        for (int tj = 0; tj < 4; ++tj)
          acc[0][ti][tj] = __builtin_amdgcn_mfma_f32_16x16x32_bf16(af[ti], bfr[tj], acc[0][ti][tj], 0, 0, 0);
    }
    {
      bf16x8 bfr[4];
#pragma unroll
      for (int t = 0; t < 4; ++t)
        bfr[t] = *(const bf16x8*)(&sBk[cur][0] + (wn + t * 16 + col) * 32 + xoq);
#pragma unroll
      for (int ti = 0; ti < 2; ++ti)
#pragma unroll
        for (int tj = 0; tj < 4; ++tj)
          acc[1][ti][tj] = __builtin_amdgcn_mfma_f32_16x16x32_bf16(af[ti], bfr[tj], acc[1][ti][tj], 0, 0, 0);
    }
    {
      bf16x8 bfr[4];
#pragma unroll
      for (int t = 0; t < 4; ++t)
        bfr[t] = *(const bf16x8*)(&sBv[cur][0] + (wn + t * 16 + col) * 32 + xoq);
#pragma unroll
      for (int ti = 0; ti < 2; ++ti)
#pragma unroll
        for (int tj = 0; tj < 4; ++tj)
          acc[2][ti][tj] = __builtin_amdgcn_mfma_f32_16x16x32_bf16(af[ti], bfr[tj], acc[2][ti][tj], 0, 0, 0);
    }
    __builtin_amdgcn_sched_barrier(0);
    __builtin_amdgcn_s_barrier();          // all waves done reading cur before restage
  }

#pragma unroll
  for (int z = 0; z < 3; ++z) {
    const float* bias = (z == 0) ? bq : (z == 1) ? bk : bv;
    unsigned short* Phi = (z == 0) ? Qhi : (z == 1) ? Khi : Vthi;
    unsigned short* Plo = (z == 0) ? Qlo : (z == 1) ? Klo : Vtlo;
    const float pre = (z == 0) ? 0.125f : 1.0f;
#pragma unroll
    for (int ti = 0; ti < 2; ++ti) {
#pragma unroll
      for (int tj = 0; tj < 4; ++tj) {
        int n = bn + wn + tj * 16 + col;
        float bv_ = bias[n];
        if (z != 2) {
#pragma unroll
          for (int i = 0; i < 4; ++i) {
            int m = bm + wm + ti * 16 + quad * 4 + i;
            float v = (acc[z][ti][tj][i] + bv_) * pre;
            unsigned short h = f32_to_bf16_rne(v);
            float hf = __uint_as_float((unsigned)h << 16);
            Phi[(size_t)m * 1024 + n] = h;
            Plo[(size_t)m * 1024 + n] = f32_to_bf16_rne(v - hf);
          }
        } else {
          int m0 = bm + wm + ti * 16 + quad * 4;  // 4 consecutive s in one batch
          u16x4 h4, l4;
#pragma unroll
          for (int i = 0; i < 4; ++i) {
            float v = acc[z][ti][tj][i] + bv_;
            unsigned short h = f32_to_bf16_rne(v);
            float hf = __uint_as_float((unsigned)h << 16);
            h4[i] = h;
            l4[i] = f32_to_bf16_rne(v - hf);
          }
          size_t idx = ((size_t)((m0 >> 10) * 1024 + n)) * 1024 + (m0 & 1023);
          *(u16x4*)(Phi + idx) = h4;
          *(u16x4*)(Plo + idx) = l4;
        }
      }
    }
  }
}

// ---------------- O-projection GEMM: 64x128 tile, double-buffered ----------------
// grid (8,64) = 512 WGs. LDS 48KB. vmcnt(6) pipeline, XCD swizzle.

__global__ __launch_bounds__(256)
void gemm_o(const unsigned short* __restrict__ A, const unsigned short* __restrict__ Bw,
            const float* __restrict__ bias, float* __restrict__ C) {
  __shared__ unsigned short sA[2][64 * 64];
  __shared__ unsigned short sB[2][128 * 64];
  const int tid = threadIdx.x;
  const int w = tid >> 6, ln = tid & 63;
  const int fid = blockIdx.y * 8 + blockIdx.x;
  const int xcd = fid & 7, sq = fid >> 3;
  const int bm = (xcd * 8 + (sq & 7)) * 64, bn = (sq >> 3) * 128;
  const int wr = (w >> 1) * 32, wc = (w & 1) * 64;
  const int quad = ln >> 4, col = ln & 15;

  f32x4 acc[2][4];
  f32x4 zero = {0.0f, 0.0f, 0.0f, 0.0f};
#pragma unroll
  for (int i = 0; i < 2; ++i)
#pragma unroll
    for (int j = 0; j < 4; ++j) acc[i][j] = zero;

  const int srow = ln >> 3;
  const int gsw  = (ln & 7) ^ srow;
  const int xo0 = (quad ^ (ln & 7)) * 8;
  const int xo1 = ((quad ^ 4) ^ (ln & 7)) * 8;

  auto STAGE = [&](int bb, int k0) {
#pragma unroll
    for (int qa = 0; qa < 2; ++qa) {
      int row = w * 16 + qa * 8 + srow;
      __builtin_amdgcn_global_load_lds(
          (const __attribute__((address_space(1))) unsigned int*)(A + (size_t)(bm + row) * 1024 + k0 + gsw * 8),
          (__attribute__((address_space(3))) unsigned int*)(&sA[bb][0] + (w * 16 + qa * 8) * 64),
          16, 0, 0);
    }
#pragma unroll
    for (int qb = 0; qb < 4; ++qb) {
      int row = w * 32 + qb * 8 + srow;
      __builtin_amdgcn_global_load_lds(
          (const __attribute__((address_space(1))) unsigned int*)(Bw + (size_t)(bn + row) * 1024 + k0 + gsw * 8),
          (__attribute__((address_space(3))) unsigned int*)(&sB[bb][0] + (w * 32 + qb * 8) * 64),
          16, 0, 0);
    }
  };

  STAGE(0, 0);
#pragma unroll 1
  for (int k0 = 0; k0 < 1024; k0 += 64) {
    const int cur = (k0 >> 6) & 1;
    if (k0 < 960) {
      STAGE(cur ^ 1, k0 + 64);
      asm volatile("s_waitcnt vmcnt(6)" ::: "memory");
    } else {
      asm volatile("s_waitcnt vmcnt(0)" ::: "memory");
    }
    __builtin_amdgcn_s_barrier();
    __builtin_amdgcn_sched_barrier(0);

    const unsigned short* pA = &sA[cur][0];
    const unsigned short* pB = &sB[cur][0];
#pragma unroll
    for (int ks = 0; ks < 2; ++ks) {
      const int xo = ks ? xo1 : xo0;
      bf16x8 af[2], bfr[4];
#pragma unroll
      for (int t = 0; t < 2; ++t)
        af[t] = *(const bf16x8*)(pA + (wr + t * 16 + col) * 64 + xo);
#pragma unroll
      for (int t = 0; t < 4; ++t)
        bfr[t] = *(const bf16x8*)(pB + (wc + t * 16 + col) * 64 + xo);
#pragma unroll
      for (int ti = 0; ti < 2; ++ti)
#pragma unroll
        for (int tj = 0; tj < 4; ++tj)
          acc[ti][tj] = __builtin_amdgcn_mfma_f32_16x16x32_bf16(af[ti], bfr[tj], acc[ti][tj], 0, 0, 0);
    }
    __builtin_amdgcn_sched_barrier(0);
    __builtin_amdgcn_s_barrier();
  }

#pragma unroll
  for (int ti = 0; ti < 2; ++ti) {
#pragma unroll
    for (int tj = 0; tj < 4; ++tj) {
      int n = bn + wc + tj * 16 + col;
      float bv_ = bias[n];
#pragma unroll
      for (int i = 0; i < 4; ++i) {
        int m = bm + wr + ti * 16 + quad * 4 + i;
        C[(size_t)m * 1024 + n] = acc[ti][tj][i] + bv_;
      }
    }
  }
}

// ---------------- MFMA flash attention, skewed QK/PV pipeline ----------
// grid (16,64), XCD-swizzled. KT=64, 4 waves x 16 q-rows. LDS 32KB (4 WGs/CU).
// S^T = K·Q^T => lane owns q=w*16+col; P register-resident via permlane swaps.
// Phase t: QK(t) + PV(t-1) MFMA back-to-back, then softmax(t) VALU (overlaps
// PV in the pipe). o-sequence {o += P(t-1)V(t-1); o *= alpha(t)} is bit-equal
// to the serial form. V staging lags K by one tile. Defer-max rescale.

__global__ __launch_bounds__(256, 4)
void attn_kernel(const unsigned short* __restrict__ Qhi, const unsigned short* __restrict__ Qlo,
                 const unsigned short* __restrict__ Khi, const unsigned short* __restrict__ Klo,
                 const unsigned short* __restrict__ Vthi, const unsigned short* __restrict__ Vtlo,
                 unsigned short* __restrict__ ctxq) {
  const int tid = threadIdx.x;
  const int id = blockIdx.y * 16 + blockIdx.x;
  const int qt = (id >> 3) & 15;
  const int bh = ((id >> 7) << 3) | (id & 7);
  const int b = bh >> 4, h = bh & 15;
  const int w = tid >> 6, ln = tid & 63, quad = ln >> 4, col = ln & 15;

  __shared__ __align__(16) short sK[16384];  // Khi@0, Klo@4096, Vthi@8192, Vtlo@12288 (shorts)

  // Q fragments (B-operand): lane holds Q[q=w*16+col][d=quad*8+e (+32 for ks=1)]
  bf16x8 qh[2], ql[2];
  {
    const size_t qoff = (size_t)(b * 1024 + qt * 64 + w * 16 + col) * 1024 + h * 64 + quad * 8;
    qh[0] = *(const bf16x8*)(Qhi + qoff);
    qh[1] = *(const bf16x8*)(Qhi + qoff + 32);
    ql[0] = *(const bf16x8*)(Qlo + qoff);
    ql[1] = *(const bf16x8*)(Qlo + qoff + 32);
  }

  // staging: wave w stages plane w into region w; K waves lead, V waves lag 1 tile
  const unsigned short* gplane = (w == 0) ? Khi : (w == 1) ? Klo : (w == 2) ? Vthi : Vtlo;
  short* splane = sK + w * 4096;
  const int r8 = ln >> 3;
  const int ch = (ln & 7) ^ r8;
  const unsigned short* bp = (w < 2)
      ? gplane + (size_t)(b * 1024 + r8) * 1024 + h * 64 + ch * 8
      : gplane + (size_t)(b * 1024 + h * 64 + r8) * 1024 + ch * 8;
  const int ktstep = (w < 2) ? 65536 : 64;

  const int xo0 = (quad ^ (col & 7)) * 8;
  const int xo1 = ((quad + 4) ^ (col & 7)) * 8;

  f32x4 o[4];
  f32x4 zero = {0.0f, 0.0f, 0.0f, 0.0f};
#pragma unroll
  for (int t = 0; t < 4; ++t) o[t] = zero;
  float m_ = -3.0e38f, l_ = 0.0f;
  bf16x8 pah[2], pal[2];  // P(t) fragments, carried across the phase boundary

  const float LOG2E = 1.44269504088896340736f;

  auto STAGE = [&]() {
#pragma unroll
    for (int g = 0; g < 8; ++g) {
      __builtin_amdgcn_global_load_lds(
          (const __attribute__((address_space(1))) unsigned int*)(bp + g * 8192),
          (__attribute__((address_space(3))) unsigned int*)(splane + g * 512),
          16, 0, 0);
    }
  };

#pragma unroll 1
  for (int kt = 0; kt < 16; ++kt) {
    __syncthreads();  // prior phase's fragment reads complete before restaging
    if (w < 2 || kt > 0) {  // K waves stage tile kt; V waves stage tile kt-1
      STAGE();
      bp += ktstep;
    }
    __syncthreads();  // staging visible (compiler drains vmcnt before barrier)

    // QK(kt): S^T = (Khi+Klo)·(Qhi+Qlo)^T, 3 cross terms (Q pre-scaled by 1/8)
    f32x4 s[4];
#pragma unroll
    for (int t = 0; t < 4; ++t) s[t] = zero;
#pragma unroll
    for (int t = 0; t < 4; ++t) {
      const int rb = (t * 16 + col) * 64;
#pragma unroll
      for (int ks = 0; ks < 2; ++ks) {
        const int xo = ks ? xo1 : xo0;
        bf16x8 kh = *(const bf16x8*)(sK +        rb + xo);
        bf16x8 kl = *(const bf16x8*)(sK + 4096 + rb + xo);
        s[t] = __builtin_amdgcn_mfma_f32_16x16x32_bf16(kh, ql[ks], s[t], 0, 0, 0);
        s[t] = __builtin_amdgcn_mfma_f32_16x16x32_bf16(kl, qh[ks], s[t], 0, 0, 0);
        s[t] = __builtin_amdgcn_mfma_f32_16x16x32_bf16(kh, qh[ks], s[t], 0, 0, 0);
      }
    }

    // PV(kt-1): O^T += (Vhi+Vlo)·(Phi+Plo)^T — independent of s, overlaps softmax
    if (kt > 0) {
#pragma unroll
      for (int nt = 0; nt < 4; ++nt) {
        const int rb = (nt * 16 + col) * 64;
#pragma unroll
        for (int ks = 0; ks < 2; ++ks) {
          const int xo = ks ? xo1 : xo0;
          bf16x8 vh = *(const bf16x8*)(sK +  8192 + rb + xo);
          bf16x8 vl = *(const bf16x8*)(sK + 12288 + rb + xo);
          o[nt] = __builtin_amdgcn_mfma_f32_16x16x32_bf16(vh, pal[ks], o[nt], 0, 0, 0);
          o[nt] = __builtin_amdgcn_mfma_f32_16x16x32_bf16(vl, pah[ks], o[nt], 0, 0, 0);
          o[nt] = __builtin_amdgcn_mfma_f32_16x16x32_bf16(vh, pah[ks], o[nt], 0, 0, 0);
        }
      }
    }

    // ---- softmax(kt): MX quantize scores, lane-local row ----
    float mx0 = fmaxf(fmaxf(fmaxf(s[0][0], s[0][1]), fmaxf(s[0][2], s[0][3])),
                      fmaxf(fmaxf(s[1][0], s[1][1]), fmaxf(s[1][2], s[1][3])));
    float mn0 = fminf(fminf(fminf(s[0][0], s[0][1]), fminf(s[0][2], s[0][3])),
                      fminf(fminf(s[1][0], s[1][1]), fminf(s[1][2], s[1][3])));
    float mx1 = fmaxf(fmaxf(fmaxf(s[2][0], s[2][1]), fmaxf(s[2][2], s[2][3])),
                      fmaxf(fmaxf(s[3][0], s[3][1]), fmaxf(s[3][2], s[3][3])));
    float mn1 = fminf(fminf(fminf(s[2][0], s[2][1]), fminf(s[2][2], s[2][3])),
                      fminf(fminf(s[3][0], s[3][1]), fminf(s[3][2], s[3][3])));
    mx0 = quad_red_max(mx0); mn0 = quad_red_min(mn0);
    mx1 = quad_red_max(mx1); mn1 = quad_red_min(mn1);

    float sc0, iv0, sc1, iv1;
    mx_scale_bits(fmaxf(mx0, -mn0), sc0, iv0);
    mx_scale_bits(fmaxf(mx1, -mn1), sc1, iv1);
    float scl0 = sc0 * LOG2E, scl1 = sc1 * LOG2E;  // fold dequant + log2e
    // quantize to e4m3 units; dequant folded into exp2 fma below
#pragma unroll
    for (int t = 0; t < 4; ++t) {
      float iv = (t < 2) ? iv0 : iv1;
      float q0 = s[t][0] * iv, q1 = s[t][1] * iv;
      qdq2(q0, q1);
      float q2 = s[t][2] * iv, q3 = s[t][3] * iv;
      qdq2(q2, q3);
      s[t][0] = q0; s[t][1] = q1; s[t][2] = q2; s[t][3] = q3;
    }
    float d0 = mx0 * iv0, d1 = mx1 * iv1;
    qdq2(d0, d1);
    float mt = fmaxf(d0 * scl0, d1 * scl1);  // row-max of quantized (qdq monotone)

    // online softmax (log2 domain), defer-max: rescale only when max grew > 4.
    // NOTE: rescale reads o AFTER PV(kt-1) accumulated — exact ordering.
    if (__any(mt > m_ + 4.0f)) {
      float mnew  = fmaxf(m_, mt);
      float alpha = __builtin_amdgcn_exp2f(m_ - mnew);
      m_ = mnew;
      l_ *= alpha;
#pragma unroll
      for (int nt = 0; nt < 4; ++nt)
#pragma unroll
        for (int i = 0; i < 4; ++i) o[nt][i] *= alpha;
    }
#pragma unroll
    for (int t = 0; t < 4; ++t) {
      float scl = (t < 2) ? scl0 : scl1;
      float p0 = __builtin_amdgcn_exp2f(__builtin_fmaf(s[t][0], scl, -m_));
      float p1 = __builtin_amdgcn_exp2f(__builtin_fmaf(s[t][1], scl, -m_));
      float p2 = __builtin_amdgcn_exp2f(__builtin_fmaf(s[t][2], scl, -m_));
      float p3 = __builtin_amdgcn_exp2f(__builtin_fmaf(s[t][3], scl, -m_));
      s[t][0] = p0; s[t][1] = p1; s[t][2] = p2; s[t][3] = p3;
      l_ += (p0 + p1) + (p2 + p3);
    }

    // ---- pack P(kt) -> bf16 hi/lo pairs; permlane redistribute to B-frags ----
    // (overwrites pah/pal AFTER PV(kt-1) consumed them)
    unsigned Wh[4][2], Wl[4][2];
#pragma unroll
    for (int t = 0; t < 4; ++t) {
#pragma unroll
      for (int u = 0; u < 2; ++u) {
        float a = s[t][2 * u], c = s[t][2 * u + 1];
        __hip_bfloat162 h2 = __float22bfloat162_rn(make_float2(a, c));
        unsigned uh = *(unsigned*)&h2;                 // lo16=bf(a), hi16=bf(c)
        float af = __uint_as_float(uh << 16);
        float cf = __uint_as_float(uh & 0xffff0000u);
        __hip_bfloat162 l2 = __float22bfloat162_rn(make_float2(a - af, c - cf));
        Wh[t][u] = uh;
        Wl[t][u] = *(unsigned*)&l2;
      }
    }
#pragma unroll
    for (int ks = 0; ks < 2; ++ks) {
      auto a0  = __builtin_amdgcn_permlane32_swap(Wh[2 * ks][0], Wh[2 * ks + 1][0], false, false);
      auto j02 = __builtin_amdgcn_permlane16_swap(a0[0], a0[1], false, false);
      auto a1  = __builtin_amdgcn_permlane32_swap(Wh[2 * ks][1], Wh[2 * ks + 1][1], false, false);
      auto j13 = __builtin_amdgcn_permlane16_swap(a1[0], a1[1], false, false);
      u32x4 hw; hw[0] = j02[0]; hw[1] = j13[0]; hw[2] = j02[1]; hw[3] = j13[1];
      pah[ks] = __builtin_bit_cast(bf16x8, hw);
      auto b0  = __builtin_amdgcn_permlane32_swap(Wl[2 * ks][0], Wl[2 * ks + 1][0], false, false);
      auto k02 = __builtin_amdgcn_permlane16_swap(b0[0], b0[1], false, false);
      auto b1  = __builtin_amdgcn_permlane32_swap(Wl[2 * ks][1], Wl[2 * ks + 1][1], false, false);
      auto k13 = __builtin_amdgcn_permlane16_swap(b1[0], b1[1], false, false);
      u32x4 lw; lw[0] = k02[0]; lw[1] = k13[0]; lw[2] = k02[1]; lw[3] = k13[1];
      pal[ks] = __builtin_bit_cast(bf16x8, lw);
    }
  }

  // drain: stage V(15), then PV(15)
  __syncthreads();
  if (w >= 2) STAGE();
  __syncthreads();
#pragma unroll
  for (int nt = 0; nt < 4; ++nt) {
    const int rb = (nt * 16 + col) * 64;
#pragma unroll
    for (int ks = 0; ks < 2; ++ks) {
      const int xo = ks ? xo1 : xo0;
      bf16x8 vh = *(const bf16x8*)(sK +  8192 + rb + xo);
      bf16x8 vl = *(const bf16x8*)(sK + 12288 + rb + xo);
      o[nt] = __builtin_amdgcn_mfma_f32_16x16x32_bf16(vh, pal[ks], o[nt], 0, 0, 0);
      o[nt] = __builtin_amdgcn_mfma_f32_16x16x32_bf16(vl, pah[ks], o[nt], 0, 0, 0);
      o[nt] = __builtin_amdgcn_mfma_f32_16x16x32_bf16(vh, pah[ks], o[nt], 0, 0, 0);
    }
  }

  // normalize + fused ctx MX quant (blocks of 32 along E = nt pairs) -> bf16
  float linv = 1.0f / quad_red_sum(l_);
#pragma unroll
  for (int nt = 0; nt < 4; ++nt)
#pragma unroll
    for (int i = 0; i < 4; ++i) o[nt][i] *= linv;

  float am0 = 0.0f, am1 = 0.0f;
#pragma unroll
  for (int i = 0; i < 4; ++i) {
    am0 = fmaxf(am0, fmaxf(__builtin_fabsf(o[0][i]), __builtin_fabsf(o[1][i])));
    am1 = fmaxf(am1, fmaxf(__builtin_fabsf(o[2][i]), __builtin_fabsf(o[3][i])));
  }
  am0 = quad_red_max(am0);
  am1 = quad_red_max(am1);
  float sc0, iv0, sc1, iv1;
  mx_scale_bits(am0, sc0, iv0);
  mx_scale_bits(am1, sc1, iv1);

  const int tok = b * 1024 + qt * 64 + w * 16 + col;
  const size_t base = (size_t)tok * 1024 + h * 64 + quad * 4;
#pragma unroll
  for (int nt = 0; nt < 4; ++nt) {
    float iv = (nt < 2) ? iv0 : iv1;
    float sc = (nt < 2) ? sc0 : sc1;
    float q0 = o[nt][0] * iv, q1 = o[nt][1] * iv;
    qdq2(q0, q1);
    float q2 = o[nt][2] * iv, q3 = o[nt][3] * iv;
    qdq2(q2, q3);
    u16x4 h4;
    h4[0] = (unsigned short)(__float_as_uint(q0 * sc) >> 16);  // exact bf16
    h4[1] = (unsigned short)(__float_as_uint(q1 * sc) >> 16);
    h4[2] = (unsigned short)(__float_as_uint(q2 * sc) >> 16);
    h4[3] = (unsigned short)(__float_as_uint(q3 * sc) >> 16);
    *(u16x4*)(ctxq + base + nt * 16) = h4;
  }
}

// ---------------- launch ----------------

extern "C" void kernel_launch(void* const* d_in, const int* in_sizes, int n_in,
                              void* d_out, int out_size, void* d_ws, size_t ws_size,
                              hipStream_t stream) {
  (void)in_sizes; (void)n_in; (void)out_size; (void)ws_size;
  const float* x  = (const float*)d_in[0];
  const float* Wq = (const float*)d_in[1];
  const float* bq = (const float*)d_in[2];
  const float* Wk = (const float*)d_in[3];
  const float* bk = (const float*)d_in[4];
  const float* Wv = (const float*)d_in[5];
  const float* bv = (const float*)d_in[6];
  const float* Wo = (const float*)d_in[7];
  const float* bo = (const float*)d_in[8];

  char* wsb = (char*)d_ws;
  const size_t MB = (size_t)1 << 20;
  unsigned short* XQb   = (unsigned short*)(wsb + 0);
  unsigned short* WQb   = (unsigned short*)(wsb + 8 * MB);
  unsigned short* WKb   = (unsigned short*)(wsb + 10 * MB);
  unsigned short* WVb   = (unsigned short*)(wsb + 12 * MB);
  unsigned short* WOb   = (unsigned short*)(wsb + 14 * MB);
  unsigned short* Qhi   = (unsigned short*)(wsb + 16 * MB);
  unsigned short* Qlo   = (unsigned short*)(wsb + 24 * MB);
  unsigned short* Khi   = (unsigned short*)(wsb + 32 * MB);
  unsigned short* Klo   = (unsigned short*)(wsb + 40 * MB);
  unsigned short* Vthi  = (unsigned short*)(wsb + 48 * MB);
  unsigned short* Vtlo  = (unsigned short*)(wsb + 56 * MB);
  unsigned short* CTXQb = XQb;  // reuse: XQ dead after V projection

  mxq_all<<<1024, 256, 0, stream>>>(x, Wq, Wk, Wv, Wo, XQb, WQb, WKb, WVb, WOb);

  dim3 qkvgrid(8, 32);  // 256 WGs = exactly 1/CU (z-merged)
  gemm_qkv<<<qkvgrid, 512, 0, stream>>>(XQb, WQb, WKb, WVb, bq, bk, bv,
                                        Qhi, Qlo, Khi, Klo, Vthi, Vtlo);

  dim3 agrid(16, 64);  // 1024 WGs, XCD-swizzled inside the kernel
  attn_kernel<<<agrid, 256, 0, stream>>>(Qhi, Qlo, Khi, Klo, Vthi, Vtlo, CTXQb);

  dim3 ogrid(E_DIM / 128, NROWS / 64);  // (8, 64) = 512 WGs
  gemm_o<<<ogrid, 256, 0, stream>>>(CTXQb, WOb, bo, (float*)d_out);
}

// Round 8
// 221.991 us; speedup vs baseline: 1.0045x; 1.0045x over previous
//
#include <hip/hip_runtime.h>
#include <hip/hip_bf16.h>
#include <cstdint>
#include <cstddef>

// MXAttention: B=4, S=1024, E=1024, H=16, D=64. fp32 in/out.
// MX quant: blocks of 32 along last/contraction dim, scale=2^(floor(log2(amax))-8),
// e4m3 grid == OCP e4m3fn. qdq = pre-clamp to +-448 then HW v_cvt_pk_fp8_f32 /
// v_cvt_f32_fp8 (RNE). Pre-clamp+convert == reference round-then-clip.
//
// GEMMs: quantized operands are e4m3 x pow2 => exactly bf16 => bf16 MFMA, fp32 acc.
// Q/K/V GEMM epilogues emit results pre-split into bf16 hi+lo planes (Q pre-scaled
// by 0.125, exact); attention uses 3 cross-term MFMAs (lo*lo dropped, ~2^-16).
// V planes stored transposed (Vt[b,h,d,s]). K/V staged via global_load_lds.
//
// gemm_qkv: R6-measured z-merged BK=64 double-buffer (one 512-thread WG computes
// the same 128x128 m,n tile for Q,K,V sharing one A stage; LDS 128KB; grid 256
// = 1 WG/CU exact; counted vmcnt(8); 2 raw barriers/K-step). BK=32 variants
// regressed twice (R3/R4, R7) — per-barrier fixed cost dominates.
//
// gemm_o (this revision): same proven 128x128/4-wave/64KB-dbuf structure as the
// R2 gemm_qkv (fp32 epilogue): grid (8,32) = 256 WGs = 1/CU exact — halves
// barrier count per output vs the old 64x128/512-WG version.
//
// attn: R7-measured skewed QK/PV pipeline — phase t computes QK(t) and PV(t-1)
// back-to-back (independent MFMA streams), then softmax(t) overlapping PV in
// the pipe. o-sequence {o += P(t-1)V(t-1); o *= alpha(t)} is bit-identical to
// the serial form. V staging lags K by one tile. Defer-max rescale.
//
// ws layout (bytes):
//   [ 0, 8)MB  XQb  bf16 quantized input; later reused as CTXQb
//   [ 8,16)MB  WQb/WKb/WVb/WOb (2 MB each)
//   [16,24) Qhi [24,32) Qlo   [32,40) Khi [40,48) Klo   [48,56) Vthi [56,64) Vtlo

#define S_LEN 1024
#define E_DIM 1024
#define NH    16
#define DH    64
#define BATCH 4
#define NROWS (BATCH * S_LEN)  // 4096

typedef short          bf16x8  __attribute__((ext_vector_type(8)));
typedef float          f32x4   __attribute__((ext_vector_type(4)));
typedef unsigned short u16x8   __attribute__((ext_vector_type(8)));
typedef unsigned short u16x4   __attribute__((ext_vector_type(4)));
typedef unsigned int   u32x4   __attribute__((ext_vector_type(4)));

// ---------------- MX quant helpers ----------------

// scale = 2^(clamp(floor(log2(amax))-8, -126, 126)), 1.0 if amax==0.
__device__ __forceinline__ void mx_scale_bits(float amax, float& scale, float& inv) {
  int eb = (int)(__float_as_uint(amax) >> 23);  // biased exponent
  int sb = eb - 8;
  sb = sb < 1 ? 1 : (sb > 253 ? 253 : sb);
  float sc = __uint_as_float((unsigned)sb << 23);
  float iv = __uint_as_float((unsigned)(254 - sb) << 23);
  bool nz = (amax > 0.0f);
  scale = nz ? sc : 1.0f;
  inv   = nz ? iv : 1.0f;
}

// round a,b to the e4m3fn grid: pre-clamp +-448 (== ref round-then-clip), HW RNE cvt.
__device__ __forceinline__ void qdq2(float& a, float& b) {
  a = fminf(fmaxf(a, -448.0f), 448.0f);
  b = fminf(fmaxf(b, -448.0f), 448.0f);
  int p = __builtin_amdgcn_cvt_pk_fp8_f32(a, b, 0, false);
  a = __builtin_amdgcn_cvt_f32_fp8(p, 0);
  b = __builtin_amdgcn_cvt_f32_fp8(p, 1);
}

__device__ __forceinline__ unsigned short f32_to_bf16_rne(float f) {
  unsigned u = __float_as_uint(f);
  unsigned r = 0x7FFFu + ((u >> 16) & 1u);
  return (unsigned short)((u + r) >> 16);
}

// ---- cross-quad (lanes ^16, ^32) all-reduce via gfx950 permlane swaps ----
__device__ __forceinline__ float quad_red_max(float x) {
  auto p = __builtin_amdgcn_permlane16_swap(__float_as_uint(x), __float_as_uint(x), false, false);
  x = fmaxf(__uint_as_float(p[0]), __uint_as_float(p[1]));
  auto q = __builtin_amdgcn_permlane32_swap(__float_as_uint(x), __float_as_uint(x), false, false);
  return fmaxf(__uint_as_float(q[0]), __uint_as_float(q[1]));
}
__device__ __forceinline__ float quad_red_min(float x) {
  auto p = __builtin_amdgcn_permlane16_swap(__float_as_uint(x), __float_as_uint(x), false, false);
  x = fminf(__uint_as_float(p[0]), __uint_as_float(p[1]));
  auto q = __builtin_amdgcn_permlane32_swap(__float_as_uint(x), __float_as_uint(x), false, false);
  return fminf(__uint_as_float(q[0]), __uint_as_float(q[1]));
}
__device__ __forceinline__ float quad_red_sum(float x) {
  auto p = __builtin_amdgcn_permlane16_swap(__float_as_uint(x), __float_as_uint(x), false, false);
  x = __uint_as_float(p[0]) + __uint_as_float(p[1]);
  auto q = __builtin_amdgcn_permlane32_swap(__float_as_uint(x), __float_as_uint(x), false, false);
  return __uint_as_float(q[0]) + __uint_as_float(q[1]);
}

// ---------------- quant kernel: fp32 in -> bf16 out (exact) ----------------

__device__ __forceinline__ void mxq_body(const float* __restrict__ in,
                                         unsigned short* __restrict__ out, int b) {
  const float4* p = (const float4*)(in + (size_t)b * 32);
  float v[32];
#pragma unroll
  for (int g = 0; g < 8; ++g) {
    float4 t = p[g];
    v[g * 4 + 0] = t.x; v[g * 4 + 1] = t.y; v[g * 4 + 2] = t.z; v[g * 4 + 3] = t.w;
  }
  float amax = 0.0f;
#pragma unroll
  for (int i = 0; i < 32; ++i) amax = fmaxf(amax, __builtin_fabsf(v[i]));
  float scale, inv;
  mx_scale_bits(amax, scale, inv);
  u16x8* q = (u16x8*)(out + (size_t)b * 32);
#pragma unroll
  for (int g = 0; g < 4; ++g) {
    u16x8 o;
#pragma unroll
    for (int e = 0; e < 8; e += 2) {
      float a = v[g * 8 + e] * inv, c = v[g * 8 + e + 1] * inv;
      qdq2(a, c);
      o[e]     = (unsigned short)(__float_as_uint(a * scale) >> 16);  // exact bf16
      o[e + 1] = (unsigned short)(__float_as_uint(c * scale) >> 16);
    }
    q[g] = o;
  }
}

// one launch quantizes x (blocks 0..511) + 4 weights (128 blocks each)
__global__ __launch_bounds__(256)
void mxq_all(const float* __restrict__ x,
             const float* __restrict__ w0, const float* __restrict__ w1,
             const float* __restrict__ w2, const float* __restrict__ w3,
             unsigned short* __restrict__ ox,
             unsigned short* __restrict__ o0, unsigned short* __restrict__ o1,
             unsigned short* __restrict__ o2, unsigned short* __restrict__ o3) {
  int blk = blockIdx.x;
  const float* in;
  unsigned short* out;
  int base;
  if (blk < 512)      { in = x;  out = ox; base = blk; }
  else if (blk < 640) { in = w0; out = o0; base = blk - 512; }
  else if (blk < 768) { in = w1; out = o1; base = blk - 640; }
  else if (blk < 896) { in = w2; out = o2; base = blk - 768; }
  else                { in = w3; out = o3; base = blk - 896; }
  mxq_body(in, out, base * 256 + threadIdx.x);
}

// ---------------- Z-merged Q/K/V bf16 MFMA NT GEMM (R6 config) ----------------
// 512 threads / 8 waves. Tile 128x128 shared across z=Q,K,V. BK=64, dbuf.
// LDS: sA + sBq + sBk + sBv, each 2x16KB = 128KB => 1 WG/CU, grid 256 = exact.
// Wave w: rows wm=(w&3)*32, cols wn=(w>>2)*64. acc[3][2][4].
// Staging: 8 gload_lds/lane/K-step (2 A + 2 per B). vmcnt(8) counted pipeline.

__global__ __launch_bounds__(512, 2)
void gemm_qkv(const unsigned short* __restrict__ XQ,
              const unsigned short* __restrict__ Wqw, const unsigned short* __restrict__ Wkw,
              const unsigned short* __restrict__ Wvw,
              const float* __restrict__ bq, const float* __restrict__ bk,
              const float* __restrict__ bv,
              unsigned short* __restrict__ Qhi, unsigned short* __restrict__ Qlo,
              unsigned short* __restrict__ Khi, unsigned short* __restrict__ Klo,
              unsigned short* __restrict__ Vthi, unsigned short* __restrict__ Vtlo) {
  __shared__ unsigned short sA [2][128 * 64];
  __shared__ unsigned short sBq[2][128 * 64];
  __shared__ unsigned short sBk[2][128 * 64];
  __shared__ unsigned short sBv[2][128 * 64];
  const int tid = threadIdx.x;
  const int w = tid >> 6, ln = tid & 63;
  // XCD-bijective swizzle over the (8,32) grid: each XCD owns 4 M-bands x 8 N.
  const int fid = blockIdx.y * 8 + blockIdx.x;
  const int xcd = fid & 7, sq = fid >> 3;
  const int bm = (xcd * 4 + (sq & 3)) * 128, bn = (sq >> 2) * 128;
  const int wm = (w & 3) * 32, wn = (w >> 2) * 64;
  const int quad = ln >> 4, col = ln & 15;

  f32x4 acc[3][2][4];
  f32x4 zero = {0.0f, 0.0f, 0.0f, 0.0f};
#pragma unroll
  for (int z = 0; z < 3; ++z)
#pragma unroll
    for (int i = 0; i < 2; ++i)
#pragma unroll
      for (int j = 0; j < 4; ++j) acc[z][i][j] = zero;

  const int srow = ln >> 3;
  const int gsw  = (ln & 7) ^ srow;          // store: LDS pos p holds chunk p^(row&7)
  const int xo0 = (quad ^ (ln & 7)) * 8;     // read: chunk quad at pos quad^(col&7)
  const int xo1 = ((quad ^ 4) ^ (ln & 7)) * 8;

  // 8 gload_lds per lane: rows j*64 + w*8 + srow for each of {A, Bq, Bk, Bv}
  auto STAGE = [&](int bb, int k0) {
#pragma unroll
    for (int j = 0; j < 2; ++j) {
      const int rowb = j * 64 + w * 8;
      const int row = rowb + srow;
      const size_t goffA = (size_t)(bm + row) * 1024 + k0 + gsw * 8;
      const size_t goffB = (size_t)(bn + row) * 1024 + k0 + gsw * 8;
      __builtin_amdgcn_global_load_lds(
          (const __attribute__((address_space(1))) unsigned int*)(XQ + goffA),
          (__attribute__((address_space(3))) unsigned int*)(&sA[bb][0] + rowb * 64),
          16, 0, 0);
      __builtin_amdgcn_global_load_lds(
          (const __attribute__((address_space(1))) unsigned int*)(Wqw + goffB),
          (__attribute__((address_space(3))) unsigned int*)(&sBq[bb][0] + rowb * 64),
          16, 0, 0);
      __builtin_amdgcn_global_load_lds(
          (const __attribute__((address_space(1))) unsigned int*)(Wkw + goffB),
          (__attribute__((address_space(3))) unsigned int*)(&sBk[bb][0] + rowb * 64),
          16, 0, 0);
      __builtin_amdgcn_global_load_lds(
          (const __attribute__((address_space(1))) unsigned int*)(Wvw + goffB),
          (__attribute__((address_space(3))) unsigned int*)(&sBv[bb][0] + rowb * 64),
          16, 0, 0);
    }
  };

  STAGE(0, 0);
#pragma unroll 1
  for (int k0 = 0; k0 < 1024; k0 += 64) {
    const int cur = (k0 >> 6) & 1;
    if (k0 < 960) {
      STAGE(cur ^ 1, k0 + 64);
      asm volatile("s_waitcnt vmcnt(8)" ::: "memory");  // this tile's 8 loads done
    } else {
      asm volatile("s_waitcnt vmcnt(0)" ::: "memory");
    }
    __builtin_amdgcn_s_barrier();          // cur fully staged & visible to all waves
    __builtin_amdgcn_sched_barrier(0);

#pragma unroll
    for (int ks = 0; ks < 2; ++ks) {
      const int xo = ks ? xo1 : xo0;
      bf16x8 af[2];
#pragma unroll
      for (int t = 0; t < 2; ++t)
        af[t] = *(const bf16x8*)(&sA[cur][0] + (wm + t * 16 + col) * 64 + xo);
      {
        bf16x8 bfr[4];
#pragma unroll
        for (int t = 0; t < 4; ++t)
          bfr[t] = *(const bf16x8*)(&sBq[cur][0] + (wn + t * 16 + col) * 64 + xo);
#pragma unroll
        for (int ti = 0; ti < 2; ++ti)
#pragma unroll
          for (int tj = 0; tj < 4; ++tj)
            acc[0][ti][tj] = __builtin_amdgcn_mfma_f32_16x16x32_bf16(af[ti], bfr[tj], acc[0][ti][tj], 0, 0, 0);
      }
      {
        bf16x8 bfr[4];
#pragma unroll
        for (int t = 0; t < 4; ++t)
          bfr[t] = *(const bf16x8*)(&sBk[cur][0] + (wn + t * 16 + col) * 64 + xo);
#pragma unroll
        for (int ti = 0; ti < 2; ++ti)
#pragma unroll
          for (int tj = 0; tj < 4; ++tj)
            acc[1][ti][tj] = __builtin_amdgcn_mfma_f32_16x16x32_bf16(af[ti], bfr[tj], acc[1][ti][tj], 0, 0, 0);
      }
      {
        bf16x8 bfr[4];
#pragma unroll
        for (int t = 0; t < 4; ++t)
          bfr[t] = *(const bf16x8*)(&sBv[cur][0] + (wn + t * 16 + col) * 64 + xo);
#pragma unroll
        for (int ti = 0; ti < 2; ++ti)
#pragma unroll
          for (int tj = 0; tj < 4; ++tj)
            acc[2][ti][tj] = __builtin_amdgcn_mfma_f32_16x16x32_bf16(af[ti], bfr[tj], acc[2][ti][tj], 0, 0, 0);
      }
    }
    __builtin_amdgcn_sched_barrier(0);
    __builtin_amdgcn_s_barrier();          // all waves done reading cur before restage
  }

#pragma unroll
  for (int z = 0; z < 3; ++z) {
    const float* bias = (z == 0) ? bq : (z == 1) ? bk : bv;
    unsigned short* Phi = (z == 0) ? Qhi : (z == 1) ? Khi : Vthi;
    unsigned short* Plo = (z == 0) ? Qlo : (z == 1) ? Klo : Vtlo;
    const float pre = (z == 0) ? 0.125f : 1.0f;
#pragma unroll
    for (int ti = 0; ti < 2; ++ti) {
#pragma unroll
      for (int tj = 0; tj < 4; ++tj) {
        int n = bn + wn + tj * 16 + col;
        float bv_ = bias[n];
        if (z != 2) {
#pragma unroll
          for (int i = 0; i < 4; ++i) {
            int m = bm + wm + ti * 16 + quad * 4 + i;
            float v = (acc[z][ti][tj][i] + bv_) * pre;
            unsigned short h = f32_to_bf16_rne(v);
            float hf = __uint_as_float((unsigned)h << 16);
            Phi[(size_t)m * 1024 + n] = h;
            Plo[(size_t)m * 1024 + n] = f32_to_bf16_rne(v - hf);
          }
        } else {
          int m0 = bm + wm + ti * 16 + quad * 4;  // 4 consecutive s in one batch
          u16x4 h4, l4;
#pragma unroll
          for (int i = 0; i < 4; ++i) {
            float v = acc[z][ti][tj][i] + bv_;
            unsigned short h = f32_to_bf16_rne(v);
            float hf = __uint_as_float((unsigned)h << 16);
            h4[i] = h;
            l4[i] = f32_to_bf16_rne(v - hf);
          }
          size_t idx = ((size_t)((m0 >> 10) * 1024 + n)) * 1024 + (m0 & 1023);
          *(u16x4*)(Phi + idx) = h4;
          *(u16x4*)(Plo + idx) = l4;
        }
      }
    }
  }
}

// ---------------- O-projection GEMM: 128x128 tile, double-buffered ----------------
// grid (8,32) = 256 WGs = 1/CU exact. 4 waves, LDS 64KB, vmcnt(8) pipeline —
// the R2-proven gemm_qkv structure with an fp32 epilogue.

__global__ __launch_bounds__(256)
void gemm_o(const unsigned short* __restrict__ A, const unsigned short* __restrict__ Bw,
            const float* __restrict__ bias, float* __restrict__ C) {
  __shared__ unsigned short sA[2][128 * 64];
  __shared__ unsigned short sB[2][128 * 64];
  const int tid = threadIdx.x;
  const int w = tid >> 6, ln = tid & 63;
  const int fid = blockIdx.y * 8 + blockIdx.x;
  const int xcd = fid & 7, sq = fid >> 3;
  const int bm = (xcd * 4 + (sq & 3)) * 128, bn = (sq >> 2) * 128;
  const int wm = (w >> 1) * 64, wn = (w & 1) * 64;
  const int quad = ln >> 4, col = ln & 15;

  f32x4 acc[4][4];
  f32x4 zero = {0.0f, 0.0f, 0.0f, 0.0f};
#pragma unroll
  for (int i = 0; i < 4; ++i)
#pragma unroll
    for (int j = 0; j < 4; ++j) acc[i][j] = zero;

  const int srow = ln >> 3;
  const int gsw  = (ln & 7) ^ srow;
  const int xo0 = (quad ^ (ln & 7)) * 8;
  const int xo1 = ((quad ^ 4) ^ (ln & 7)) * 8;

  auto STAGE = [&](int bb, int k0) {
#pragma unroll
    for (int q = 0; q < 4; ++q) {
      int row = w * 32 + q * 8 + srow;
      __builtin_amdgcn_global_load_lds(
          (const __attribute__((address_space(1))) unsigned int*)(A + (size_t)(bm + row) * 1024 + k0 + gsw * 8),
          (__attribute__((address_space(3))) unsigned int*)(&sA[bb][0] + (w * 32 + q * 8) * 64),
          16, 0, 0);
      __builtin_amdgcn_global_load_lds(
          (const __attribute__((address_space(1))) unsigned int*)(Bw + (size_t)(bn + row) * 1024 + k0 + gsw * 8),
          (__attribute__((address_space(3))) unsigned int*)(&sB[bb][0] + (w * 32 + q * 8) * 64),
          16, 0, 0);
    }
  };

  STAGE(0, 0);
#pragma unroll 1
  for (int k0 = 0; k0 < 1024; k0 += 64) {
    const int cur = (k0 >> 6) & 1;
    if (k0 < 960) {
      STAGE(cur ^ 1, k0 + 64);
      asm volatile("s_waitcnt vmcnt(8)" ::: "memory");
    } else {
      asm volatile("s_waitcnt vmcnt(0)" ::: "memory");
    }
    __builtin_amdgcn_s_barrier();
    __builtin_amdgcn_sched_barrier(0);

    const unsigned short* pA = &sA[cur][0];
    const unsigned short* pB = &sB[cur][0];
#pragma unroll
    for (int ks = 0; ks < 2; ++ks) {
      const int xo = ks ? xo1 : xo0;
      bf16x8 af[4], bfr[4];
#pragma unroll
      for (int t = 0; t < 4; ++t) {
        af[t]  = *(const bf16x8*)(pA + (wm + t * 16 + col) * 64 + xo);
        bfr[t] = *(const bf16x8*)(pB + (wn + t * 16 + col) * 64 + xo);
      }
#pragma unroll
      for (int ti = 0; ti < 4; ++ti)
#pragma unroll
        for (int tj = 0; tj < 4; ++tj)
          acc[ti][tj] = __builtin_amdgcn_mfma_f32_16x16x32_bf16(af[ti], bfr[tj], acc[ti][tj], 0, 0, 0);
    }
    __builtin_amdgcn_sched_barrier(0);
    __builtin_amdgcn_s_barrier();
  }

#pragma unroll
  for (int ti = 0; ti < 4; ++ti) {
#pragma unroll
    for (int tj = 0; tj < 4; ++tj) {
      int n = bn + wn + tj * 16 + col;
      float bv_ = bias[n];
#pragma unroll
      for (int i = 0; i < 4; ++i) {
        int m = bm + wm + ti * 16 + quad * 4 + i;
        C[(size_t)m * 1024 + n] = acc[ti][tj][i] + bv_;
      }
    }
  }
}

// ---------------- MFMA flash attention, skewed QK/PV pipeline (R7) ----------
// grid (16,64), XCD-swizzled. KT=64, 4 waves x 16 q-rows. LDS 32KB (4 WGs/CU).
// S^T = K·Q^T => lane owns q=w*16+col; P register-resident via permlane swaps.
// Phase t: QK(t) + PV(t-1) MFMA back-to-back, then softmax(t) VALU (overlaps
// PV in the pipe). o-sequence {o += P(t-1)V(t-1); o *= alpha(t)} is bit-equal
// to the serial form. V staging lags K by one tile. Defer-max rescale.

__global__ __launch_bounds__(256, 4)
void attn_kernel(const unsigned short* __restrict__ Qhi, const unsigned short* __restrict__ Qlo,
                 const unsigned short* __restrict__ Khi, const unsigned short* __restrict__ Klo,
                 const unsigned short* __restrict__ Vthi, const unsigned short* __restrict__ Vtlo,
                 unsigned short* __restrict__ ctxq) {
  const int tid = threadIdx.x;
  const int id = blockIdx.y * 16 + blockIdx.x;
  const int qt = (id >> 3) & 15;
  const int bh = ((id >> 7) << 3) | (id & 7);
  const int b = bh >> 4, h = bh & 15;
  const int w = tid >> 6, ln = tid & 63, quad = ln >> 4, col = ln & 15;

  __shared__ __align__(16) short sK[16384];  // Khi@0, Klo@4096, Vthi@8192, Vtlo@12288 (shorts)

  // Q fragments (B-operand): lane holds Q[q=w*16+col][d=quad*8+e (+32 for ks=1)]
  bf16x8 qh[2], ql[2];
  {
    const size_t qoff = (size_t)(b * 1024 + qt * 64 + w * 16 + col) * 1024 + h * 64 + quad * 8;
    qh[0] = *(const bf16x8*)(Qhi + qoff);
    qh[1] = *(const bf16x8*)(Qhi + qoff + 32);
    ql[0] = *(const bf16x8*)(Qlo + qoff);
    ql[1] = *(const bf16x8*)(Qlo + qoff + 32);
  }

  // staging: wave w stages plane w into region w; K waves lead, V waves lag 1 tile
  const unsigned short* gplane = (w == 0) ? Khi : (w == 1) ? Klo : (w == 2) ? Vthi : Vtlo;
  short* splane = sK + w * 4096;
  const int r8 = ln >> 3;
  const int ch = (ln & 7) ^ r8;
  const unsigned short* bp = (w < 2)
      ? gplane + (size_t)(b * 1024 + r8) * 1024 + h * 64 + ch * 8
      : gplane + (size_t)(b * 1024 + h * 64 + r8) * 1024 + ch * 8;
  const int ktstep = (w < 2) ? 65536 : 64;

  const int xo0 = (quad ^ (col & 7)) * 8;
  const int xo1 = ((quad + 4) ^ (col & 7)) * 8;

  f32x4 o[4];
  f32x4 zero = {0.0f, 0.0f, 0.0f, 0.0f};
#pragma unroll
  for (int t = 0; t < 4; ++t) o[t] = zero;
  float m_ = -3.0e38f, l_ = 0.0f;
  bf16x8 pah[2], pal[2];  // P(t) fragments, carried across the phase boundary

  const float LOG2E = 1.44269504088896340736f;

  auto STAGE = [&]() {
#pragma unroll
    for (int g = 0; g < 8; ++g) {
      __builtin_amdgcn_global_load_lds(
          (const __attribute__((address_space(1))) unsigned int*)(bp + g * 8192),
          (__attribute__((address_space(3))) unsigned int*)(splane + g * 512),
          16, 0, 0);
    }
  };

#pragma unroll 1
  for (int kt = 0; kt < 16; ++kt) {
    __syncthreads();  // prior phase's fragment reads complete before restaging
    if (w < 2 || kt > 0) {  // K waves stage tile kt; V waves stage tile kt-1
      STAGE();
      bp += ktstep;
    }
    __syncthreads();  // staging visible (compiler drains vmcnt before barrier)

    // QK(kt): S^T = (Khi+Klo)·(Qhi+Qlo)^T, 3 cross terms (Q pre-scaled by 1/8)
    f32x4 s[4];
#pragma unroll
    for (int t = 0; t < 4; ++t) s[t] = zero;
#pragma unroll
    for (int t = 0; t < 4; ++t) {
      const int rb = (t * 16 + col) * 64;
#pragma unroll
      for (int ks = 0; ks < 2; ++ks) {
        const int xo = ks ? xo1 : xo0;
        bf16x8 kh = *(const bf16x8*)(sK +        rb + xo);
        bf16x8 kl = *(const bf16x8*)(sK + 4096 + rb + xo);
        s[t] = __builtin_amdgcn_mfma_f32_16x16x32_bf16(kh, ql[ks], s[t], 0, 0, 0);
        s[t] = __builtin_amdgcn_mfma_f32_16x16x32_bf16(kl, qh[ks], s[t], 0, 0, 0);
        s[t] = __builtin_amdgcn_mfma_f32_16x16x32_bf16(kh, qh[ks], s[t], 0, 0, 0);
      }
    }

    // PV(kt-1): O^T += (Vhi+Vlo)·(Phi+Plo)^T — independent of s, overlaps softmax
    if (kt > 0) {
#pragma unroll
      for (int nt = 0; nt < 4; ++nt) {
        const int rb = (nt * 16 + col) * 64;
#pragma unroll
        for (int ks = 0; ks < 2; ++ks) {
          const int xo = ks ? xo1 : xo0;
          bf16x8 vh = *(const bf16x8*)(sK +  8192 + rb + xo);
          bf16x8 vl = *(const bf16x8*)(sK + 12288 + rb + xo);
          o[nt] = __builtin_amdgcn_mfma_f32_16x16x32_bf16(vh, pal[ks], o[nt], 0, 0, 0);
          o[nt] = __builtin_amdgcn_mfma_f32_16x16x32_bf16(vl, pah[ks], o[nt], 0, 0, 0);
          o[nt] = __builtin_amdgcn_mfma_f32_16x16x32_bf16(vh, pah[ks], o[nt], 0, 0, 0);
        }
      }
    }

    // ---- softmax(kt): MX quantize scores, lane-local row ----
    float mx0 = fmaxf(fmaxf(fmaxf(s[0][0], s[0][1]), fmaxf(s[0][2], s[0][3])),
                      fmaxf(fmaxf(s[1][0], s[1][1]), fmaxf(s[1][2], s[1][3])));
    float mn0 = fminf(fminf(fminf(s[0][0], s[0][1]), fminf(s[0][2], s[0][3])),
                      fminf(fminf(s[1][0], s[1][1]), fminf(s[1][2], s[1][3])));
    float mx1 = fmaxf(fmaxf(fmaxf(s[2][0], s[2][1]), fmaxf(s[2][2], s[2][3])),
                      fmaxf(fmaxf(s[3][0], s[3][1]), fmaxf(s[3][2], s[3][3])));
    float mn1 = fminf(fminf(fminf(s[2][0], s[2][1]), fminf(s[2][2], s[2][3])),
                      fminf(fminf(s[3][0], s[3][1]), fminf(s[3][2], s[3][3])));
    mx0 = quad_red_max(mx0); mn0 = quad_red_min(mn0);
    mx1 = quad_red_max(mx1); mn1 = quad_red_min(mn1);

    float sc0, iv0, sc1, iv1;
    mx_scale_bits(fmaxf(mx0, -mn0), sc0, iv0);
    mx_scale_bits(fmaxf(mx1, -mn1), sc1, iv1);
    float scl0 = sc0 * LOG2E, scl1 = sc1 * LOG2E;  // fold dequant + log2e
    // quantize to e4m3 units; dequant folded into exp2 fma below
#pragma unroll
    for (int t = 0; t < 4; ++t) {
      float iv = (t < 2) ? iv0 : iv1;
      float q0 = s[t][0] * iv, q1 = s[t][1] * iv;
      qdq2(q0, q1);
      float q2 = s[t][2] * iv, q3 = s[t][3] * iv;
      qdq2(q2, q3);
      s[t][0] = q0; s[t][1] = q1; s[t][2] = q2; s[t][3] = q3;
    }
    float d0 = mx0 * iv0, d1 = mx1 * iv1;
    qdq2(d0, d1);
    float mt = fmaxf(d0 * scl0, d1 * scl1);  // row-max of quantized (qdq monotone)

    // online softmax (log2 domain), defer-max: rescale only when max grew > 4.
    // NOTE: rescale reads o AFTER PV(kt-1) accumulated — exact ordering.
    if (__any(mt > m_ + 4.0f)) {
      float mnew  = fmaxf(m_, mt);
      float alpha = __builtin_amdgcn_exp2f(m_ - mnew);
      m_ = mnew;
      l_ *= alpha;
#pragma unroll
      for (int nt = 0; nt < 4; ++nt)
#pragma unroll
        for (int i = 0; i < 4; ++i) o[nt][i] *= alpha;
    }
#pragma unroll
    for (int t = 0; t < 4; ++t) {
      float scl = (t < 2) ? scl0 : scl1;
      float p0 = __builtin_amdgcn_exp2f(__builtin_fmaf(s[t][0], scl, -m_));
      float p1 = __builtin_amdgcn_exp2f(__builtin_fmaf(s[t][1], scl, -m_));
      float p2 = __builtin_amdgcn_exp2f(__builtin_fmaf(s[t][2], scl, -m_));
      float p3 = __builtin_amdgcn_exp2f(__builtin_fmaf(s[t][3], scl, -m_));
      s[t][0] = p0; s[t][1] = p1; s[t][2] = p2; s[t][3] = p3;
      l_ += (p0 + p1) + (p2 + p3);
    }

    // ---- pack P(kt) -> bf16 hi/lo pairs; permlane redistribute to B-frags ----
    // (overwrites pah/pal AFTER PV(kt-1) consumed them)
    unsigned Wh[4][2], Wl[4][2];
#pragma unroll
    for (int t = 0; t < 4; ++t) {
#pragma unroll
      for (int u = 0; u < 2; ++u) {
        float a = s[t][2 * u], c = s[t][2 * u + 1];
        __hip_bfloat162 h2 = __float22bfloat162_rn(make_float2(a, c));
        unsigned uh = *(unsigned*)&h2;                 // lo16=bf(a), hi16=bf(c)
        float af = __uint_as_float(uh << 16);
        float cf = __uint_as_float(uh & 0xffff0000u);
        __hip_bfloat162 l2 = __float22bfloat162_rn(make_float2(a - af, c - cf));
        Wh[t][u] = uh;
        Wl[t][u] = *(unsigned*)&l2;
      }
    }
#pragma unroll
    for (int ks = 0; ks < 2; ++ks) {
      auto a0  = __builtin_amdgcn_permlane32_swap(Wh[2 * ks][0], Wh[2 * ks + 1][0], false, false);
      auto j02 = __builtin_amdgcn_permlane16_swap(a0[0], a0[1], false, false);
      auto a1  = __builtin_amdgcn_permlane32_swap(Wh[2 * ks][1], Wh[2 * ks + 1][1], false, false);
      auto j13 = __builtin_amdgcn_permlane16_swap(a1[0], a1[1], false, false);
      u32x4 hw; hw[0] = j02[0]; hw[1] = j13[0]; hw[2] = j02[1]; hw[3] = j13[1];
      pah[ks] = __builtin_bit_cast(bf16x8, hw);
      auto b0  = __builtin_amdgcn_permlane32_swap(Wl[2 * ks][0], Wl[2 * ks + 1][0], false, false);
      auto k02 = __builtin_amdgcn_permlane16_swap(b0[0], b0[1], false, false);
      auto b1  = __builtin_amdgcn_permlane32_swap(Wl[2 * ks][1], Wl[2 * ks + 1][1], false, false);
      auto k13 = __builtin_amdgcn_permlane16_swap(b1[0], b1[1], false, false);
      u32x4 lw; lw[0] = k02[0]; lw[1] = k13[0]; lw[2] = k02[1]; lw[3] = k13[1];
      pal[ks] = __builtin_bit_cast(bf16x8, lw);
    }
  }

  // drain: stage V(15), then PV(15)
  __syncthreads();
  if (w >= 2) STAGE();
  __syncthreads();
#pragma unroll
  for (int nt = 0; nt < 4; ++nt) {
    const int rb = (nt * 16 + col) * 64;
#pragma unroll
    for (int ks = 0; ks < 2; ++ks) {
      const int xo = ks ? xo1 : xo0;
      bf16x8 vh = *(const bf16x8*)(sK +  8192 + rb + xo);
      bf16x8 vl = *(const bf16x8*)(sK + 12288 + rb + xo);
      o[nt] = __builtin_amdgcn_mfma_f32_16x16x32_bf16(vh, pal[ks], o[nt], 0, 0, 0);
      o[nt] = __builtin_amdgcn_mfma_f32_16x16x32_bf16(vl, pah[ks], o[nt], 0, 0, 0);
      o[nt] = __builtin_amdgcn_mfma_f32_16x16x32_bf16(vh, pah[ks], o[nt], 0, 0, 0);
    }
  }

  // normalize + fused ctx MX quant (blocks of 32 along E = nt pairs) -> bf16
  float linv = 1.0f / quad_red_sum(l_);
#pragma unroll
  for (int nt = 0; nt < 4; ++nt)
#pragma unroll
    for (int i = 0; i < 4; ++i) o[nt][i] *= linv;

  float am0 = 0.0f, am1 = 0.0f;
#pragma unroll
  for (int i = 0; i < 4; ++i) {
    am0 = fmaxf(am0, fmaxf(__builtin_fabsf(o[0][i]), __builtin_fabsf(o[1][i])));
    am1 = fmaxf(am1, fmaxf(__builtin_fabsf(o[2][i]), __builtin_fabsf(o[3][i])));
  }
  am0 = quad_red_max(am0);
  am1 = quad_red_max(am1);
  float sc0, iv0, sc1, iv1;
  mx_scale_bits(am0, sc0, iv0);
  mx_scale_bits(am1, sc1, iv1);

  const int tok = b * 1024 + qt * 64 + w * 16 + col;
  const size_t base = (size_t)tok * 1024 + h * 64 + quad * 4;
#pragma unroll
  for (int nt = 0; nt < 4; ++nt) {
    float iv = (nt < 2) ? iv0 : iv1;
    float sc = (nt < 2) ? sc0 : sc1;
    float q0 = o[nt][0] * iv, q1 = o[nt][1] * iv;
    qdq2(q0, q1);
    float q2 = o[nt][2] * iv, q3 = o[nt][3] * iv;
    qdq2(q2, q3);
    u16x4 h4;
    h4[0] = (unsigned short)(__float_as_uint(q0 * sc) >> 16);  // exact bf16
    h4[1] = (unsigned short)(__float_as_uint(q1 * sc) >> 16);
    h4[2] = (unsigned short)(__float_as_uint(q2 * sc) >> 16);
    h4[3] = (unsigned short)(__float_as_uint(q3 * sc) >> 16);
    *(u16x4*)(ctxq + base + nt * 16) = h4;
  }
}

// ---------------- launch ----------------

extern "C" void kernel_launch(void* const* d_in, const int* in_sizes, int n_in,
                              void* d_out, int out_size, void* d_ws, size_t ws_size,
                              hipStream_t stream) {
  (void)in_sizes; (void)n_in; (void)out_size; (void)ws_size;
  const float* x  = (const float*)d_in[0];
  const float* Wq = (const float*)d_in[1];
  const float* bq = (const float*)d_in[2];
  const float* Wk = (const float*)d_in[3];
  const float* bk = (const float*)d_in[4];
  const float* Wv = (const float*)d_in[5];
  const float* bv = (const float*)d_in[6];
  const float* Wo = (const float*)d_in[7];
  const float* bo = (const float*)d_in[8];

  char* wsb = (char*)d_ws;
  const size_t MB = (size_t)1 << 20;
  unsigned short* XQb   = (unsigned short*)(wsb + 0);
  unsigned short* WQb   = (unsigned short*)(wsb + 8 * MB);
  unsigned short* WKb   = (unsigned short*)(wsb + 10 * MB);
  unsigned short* WVb   = (unsigned short*)(wsb + 12 * MB);
  unsigned short* WOb   = (unsigned short*)(wsb + 14 * MB);
  unsigned short* Qhi   = (unsigned short*)(wsb + 16 * MB);
  unsigned short* Qlo   = (unsigned short*)(wsb + 24 * MB);
  unsigned short* Khi   = (unsigned short*)(wsb + 32 * MB);
  unsigned short* Klo   = (unsigned short*)(wsb + 40 * MB);
  unsigned short* Vthi  = (unsigned short*)(wsb + 48 * MB);
  unsigned short* Vtlo  = (unsigned short*)(wsb + 56 * MB);
  unsigned short* CTXQb = XQb;  // reuse: XQ dead after V projection

  mxq_all<<<1024, 256, 0, stream>>>(x, Wq, Wk, Wv, Wo, XQb, WQb, WKb, WVb, WOb);

  dim3 qkvgrid(8, 32);  // 256 WGs = exactly 1/CU (z-merged)
  gemm_qkv<<<qkvgrid, 512, 0, stream>>>(XQb, WQb, WKb, WVb, bq, bk, bv,
                                        Qhi, Qlo, Khi, Klo, Vthi, Vtlo);

  dim3 agrid(16, 64);  // 1024 WGs, XCD-swizzled inside the kernel
  attn_kernel<<<agrid, 256, 0, stream>>>(Qhi, Qlo, Khi, Klo, Vthi, Vtlo, CTXQb);

  dim3 ogrid(8, 32);  // 256 WGs = exactly 1/CU
  gemm_o<<<ogrid, 256, 0, stream>>>(CTXQb, WOb, bo, (float*)d_out);
}

// Round 9
// 214.768 us; speedup vs baseline: 1.0383x; 1.0336x over previous
//
#include <hip/hip_runtime.h>
#include <hip/hip_bf16.h>
#include <cstdint>
#include <cstddef>

// MXAttention: B=4, S=1024, E=1024, H=16, D=64. fp32 in/out.
// MX quant: blocks of 32 along last/contraction dim, scale=2^(floor(log2(amax))-8),
// e4m3 grid == OCP e4m3fn. qdq = pre-clamp to +-448 then HW v_cvt_pk_fp8_f32 /
// v_cvt_f32_fp8 (RNE). Pre-clamp+convert == reference round-then-clip.
//
// GEMMs: quantized operands are e4m3 x pow2 => exactly bf16 => bf16 MFMA, fp32 acc.
// Q/K/V GEMM epilogues emit results pre-split into bf16 hi+lo planes (Q pre-scaled
// by 0.125, exact); attention uses 3 cross-term MFMAs (lo*lo dropped, ~2^-16).
// V planes stored transposed (Vt[b,h,d,s]). K/V staged via global_load_lds.
//
// BEST-OF BUILD (per-kernel best measured variants):
//  - gemm_qkv: R6 z-merged BK=64 dbuf (512 thr / 8 waves, LDS 128KB, grid 256
//    = 1 WG/CU, vmcnt(8)). BK=32 regressed twice (fixed per-barrier cost).
//  - gemm_o: R6 64x128 / 512 WGs / 2 WG/CU (8 waves/CU). The 128x128/256-WG
//    variant regressed ~6us: 256-thread WG at 1 WG/CU = only 4 waves/CU.
//  - attn: R7/R8 skewed QK/PV pipeline (82.5us): phase t runs QK(t)+PV(t-1)
//    back-to-back, softmax(t) overlaps PV in the pipe; o-sequence
//    {o += P(t-1)V(t-1); o *= alpha(t)} is bit-identical to serial. V staging
//    lags K one tile. Defer-max rescale; fma-folded exp2.
//
// ws layout (bytes):
//   [ 0, 8)MB  XQb  bf16 quantized input; later reused as CTXQb
//   [ 8,16)MB  WQb/WKb/WVb/WOb (2 MB each)
//   [16,24) Qhi [24,32) Qlo   [32,40) Khi [40,48) Klo   [48,56) Vthi [56,64) Vtlo

#define S_LEN 1024
#define E_DIM 1024
#define NH    16
#define DH    64
#define BATCH 4
#define NROWS (BATCH * S_LEN)  // 4096

typedef short          bf16x8  __attribute__((ext_vector_type(8)));
typedef float          f32x4   __attribute__((ext_vector_type(4)));
typedef unsigned short u16x8   __attribute__((ext_vector_type(8)));
typedef unsigned short u16x4   __attribute__((ext_vector_type(4)));
typedef unsigned int   u32x4   __attribute__((ext_vector_type(4)));

// ---------------- MX quant helpers ----------------

// scale = 2^(clamp(floor(log2(amax))-8, -126, 126)), 1.0 if amax==0.
__device__ __forceinline__ void mx_scale_bits(float amax, float& scale, float& inv) {
  int eb = (int)(__float_as_uint(amax) >> 23);  // biased exponent
  int sb = eb - 8;
  sb = sb < 1 ? 1 : (sb > 253 ? 253 : sb);
  float sc = __uint_as_float((unsigned)sb << 23);
  float iv = __uint_as_float((unsigned)(254 - sb) << 23);
  bool nz = (amax > 0.0f);
  scale = nz ? sc : 1.0f;
  inv   = nz ? iv : 1.0f;
}

// round a,b to the e4m3fn grid: pre-clamp +-448 (== ref round-then-clip), HW RNE cvt.
__device__ __forceinline__ void qdq2(float& a, float& b) {
  a = fminf(fmaxf(a, -448.0f), 448.0f);
  b = fminf(fmaxf(b, -448.0f), 448.0f);
  int p = __builtin_amdgcn_cvt_pk_fp8_f32(a, b, 0, false);
  a = __builtin_amdgcn_cvt_f32_fp8(p, 0);
  b = __builtin_amdgcn_cvt_f32_fp8(p, 1);
}

__device__ __forceinline__ unsigned short f32_to_bf16_rne(float f) {
  unsigned u = __float_as_uint(f);
  unsigned r = 0x7FFFu + ((u >> 16) & 1u);
  return (unsigned short)((u + r) >> 16);
}

// ---- cross-quad (lanes ^16, ^32) all-reduce via gfx950 permlane swaps ----
__device__ __forceinline__ float quad_red_max(float x) {
  auto p = __builtin_amdgcn_permlane16_swap(__float_as_uint(x), __float_as_uint(x), false, false);
  x = fmaxf(__uint_as_float(p[0]), __uint_as_float(p[1]));
  auto q = __builtin_amdgcn_permlane32_swap(__float_as_uint(x), __float_as_uint(x), false, false);
  return fmaxf(__uint_as_float(q[0]), __uint_as_float(q[1]));
}
__device__ __forceinline__ float quad_red_min(float x) {
  auto p = __builtin_amdgcn_permlane16_swap(__float_as_uint(x), __float_as_uint(x), false, false);
  x = fminf(__uint_as_float(p[0]), __uint_as_float(p[1]));
  auto q = __builtin_amdgcn_permlane32_swap(__float_as_uint(x), __float_as_uint(x), false, false);
  return fminf(__uint_as_float(q[0]), __uint_as_float(q[1]));
}
__device__ __forceinline__ float quad_red_sum(float x) {
  auto p = __builtin_amdgcn_permlane16_swap(__float_as_uint(x), __float_as_uint(x), false, false);
  x = __uint_as_float(p[0]) + __uint_as_float(p[1]);
  auto q = __builtin_amdgcn_permlane32_swap(__float_as_uint(x), __float_as_uint(x), false, false);
  return __uint_as_float(q[0]) + __uint_as_float(q[1]);
}

// ---------------- quant kernel: fp32 in -> bf16 out (exact) ----------------

__device__ __forceinline__ void mxq_body(const float* __restrict__ in,
                                         unsigned short* __restrict__ out, int b) {
  const float4* p = (const float4*)(in + (size_t)b * 32);
  float v[32];
#pragma unroll
  for (int g = 0; g < 8; ++g) {
    float4 t = p[g];
    v[g * 4 + 0] = t.x; v[g * 4 + 1] = t.y; v[g * 4 + 2] = t.z; v[g * 4 + 3] = t.w;
  }
  float amax = 0.0f;
#pragma unroll
  for (int i = 0; i < 32; ++i) amax = fmaxf(amax, __builtin_fabsf(v[i]));
  float scale, inv;
  mx_scale_bits(amax, scale, inv);
  u16x8* q = (u16x8*)(out + (size_t)b * 32);
#pragma unroll
  for (int g = 0; g < 4; ++g) {
    u16x8 o;
#pragma unroll
    for (int e = 0; e < 8; e += 2) {
      float a = v[g * 8 + e] * inv, c = v[g * 8 + e + 1] * inv;
      qdq2(a, c);
      o[e]     = (unsigned short)(__float_as_uint(a * scale) >> 16);  // exact bf16
      o[e + 1] = (unsigned short)(__float_as_uint(c * scale) >> 16);
    }
    q[g] = o;
  }
}

// one launch quantizes x (blocks 0..511) + 4 weights (128 blocks each)
__global__ __launch_bounds__(256)
void mxq_all(const float* __restrict__ x,
             const float* __restrict__ w0, const float* __restrict__ w1,
             const float* __restrict__ w2, const float* __restrict__ w3,
             unsigned short* __restrict__ ox,
             unsigned short* __restrict__ o0, unsigned short* __restrict__ o1,
             unsigned short* __restrict__ o2, unsigned short* __restrict__ o3) {
  int blk = blockIdx.x;
  const float* in;
  unsigned short* out;
  int base;
  if (blk < 512)      { in = x;  out = ox; base = blk; }
  else if (blk < 640) { in = w0; out = o0; base = blk - 512; }
  else if (blk < 768) { in = w1; out = o1; base = blk - 640; }
  else if (blk < 896) { in = w2; out = o2; base = blk - 768; }
  else                { in = w3; out = o3; base = blk - 896; }
  mxq_body(in, out, base * 256 + threadIdx.x);
}

// ---------------- Z-merged Q/K/V bf16 MFMA NT GEMM (R6 config) ----------------
// 512 threads / 8 waves. Tile 128x128 shared across z=Q,K,V. BK=64, dbuf.
// LDS: sA + sBq + sBk + sBv, each 2x16KB = 128KB => 1 WG/CU, grid 256 = exact.
// Wave w: rows wm=(w&3)*32, cols wn=(w>>2)*64. acc[3][2][4].
// Staging: 8 gload_lds/lane/K-step (2 A + 2 per B). vmcnt(8) counted pipeline.

__global__ __launch_bounds__(512, 2)
void gemm_qkv(const unsigned short* __restrict__ XQ,
              const unsigned short* __restrict__ Wqw, const unsigned short* __restrict__ Wkw,
              const unsigned short* __restrict__ Wvw,
              const float* __restrict__ bq, const float* __restrict__ bk,
              const float* __restrict__ bv,
              unsigned short* __restrict__ Qhi, unsigned short* __restrict__ Qlo,
              unsigned short* __restrict__ Khi, unsigned short* __restrict__ Klo,
              unsigned short* __restrict__ Vthi, unsigned short* __restrict__ Vtlo) {
  __shared__ unsigned short sA [2][128 * 64];
  __shared__ unsigned short sBq[2][128 * 64];
  __shared__ unsigned short sBk[2][128 * 64];
  __shared__ unsigned short sBv[2][128 * 64];
  const int tid = threadIdx.x;
  const int w = tid >> 6, ln = tid & 63;
  // XCD-bijective swizzle over the (8,32) grid: each XCD owns 4 M-bands x 8 N.
  const int fid = blockIdx.y * 8 + blockIdx.x;
  const int xcd = fid & 7, sq = fid >> 3;
  const int bm = (xcd * 4 + (sq & 3)) * 128, bn = (sq >> 2) * 128;
  const int wm = (w & 3) * 32, wn = (w >> 2) * 64;
  const int quad = ln >> 4, col = ln & 15;

  f32x4 acc[3][2][4];
  f32x4 zero = {0.0f, 0.0f, 0.0f, 0.0f};
#pragma unroll
  for (int z = 0; z < 3; ++z)
#pragma unroll
    for (int i = 0; i < 2; ++i)
#pragma unroll
      for (int j = 0; j < 4; ++j) acc[z][i][j] = zero;

  const int srow = ln >> 3;
  const int gsw  = (ln & 7) ^ srow;          // store: LDS pos p holds chunk p^(row&7)
  const int xo0 = (quad ^ (ln & 7)) * 8;     // read: chunk quad at pos quad^(col&7)
  const int xo1 = ((quad ^ 4) ^ (ln & 7)) * 8;

  // 8 gload_lds per lane: rows j*64 + w*8 + srow for each of {A, Bq, Bk, Bv}
  auto STAGE = [&](int bb, int k0) {
#pragma unroll
    for (int j = 0; j < 2; ++j) {
      const int rowb = j * 64 + w * 8;
      const int row = rowb + srow;
      const size_t goffA = (size_t)(bm + row) * 1024 + k0 + gsw * 8;
      const size_t goffB = (size_t)(bn + row) * 1024 + k0 + gsw * 8;
      __builtin_amdgcn_global_load_lds(
          (const __attribute__((address_space(1))) unsigned int*)(XQ + goffA),
          (__attribute__((address_space(3))) unsigned int*)(&sA[bb][0] + rowb * 64),
          16, 0, 0);
      __builtin_amdgcn_global_load_lds(
          (const __attribute__((address_space(1))) unsigned int*)(Wqw + goffB),
          (__attribute__((address_space(3))) unsigned int*)(&sBq[bb][0] + rowb * 64),
          16, 0, 0);
      __builtin_amdgcn_global_load_lds(
          (const __attribute__((address_space(1))) unsigned int*)(Wkw + goffB),
          (__attribute__((address_space(3))) unsigned int*)(&sBk[bb][0] + rowb * 64),
          16, 0, 0);
      __builtin_amdgcn_global_load_lds(
          (const __attribute__((address_space(1))) unsigned int*)(Wvw + goffB),
          (__attribute__((address_space(3))) unsigned int*)(&sBv[bb][0] + rowb * 64),
          16, 0, 0);
    }
  };

  STAGE(0, 0);
#pragma unroll 1
  for (int k0 = 0; k0 < 1024; k0 += 64) {
    const int cur = (k0 >> 6) & 1;
    if (k0 < 960) {
      STAGE(cur ^ 1, k0 + 64);
      asm volatile("s_waitcnt vmcnt(8)" ::: "memory");  // this tile's 8 loads done
    } else {
      asm volatile("s_waitcnt vmcnt(0)" ::: "memory");
    }
    __builtin_amdgcn_s_barrier();          // cur fully staged & visible to all waves
    __builtin_amdgcn_sched_barrier(0);

#pragma unroll
    for (int ks = 0; ks < 2; ++ks) {
      const int xo = ks ? xo1 : xo0;
      bf16x8 af[2];
#pragma unroll
      for (int t = 0; t < 2; ++t)
        af[t] = *(const bf16x8*)(&sA[cur][0] + (wm + t * 16 + col) * 64 + xo);
      {
        bf16x8 bfr[4];
#pragma unroll
        for (int t = 0; t < 4; ++t)
          bfr[t] = *(const bf16x8*)(&sBq[cur][0] + (wn + t * 16 + col) * 64 + xo);
#pragma unroll
        for (int ti = 0; ti < 2; ++ti)
#pragma unroll
          for (int tj = 0; tj < 4; ++tj)
            acc[0][ti][tj] = __builtin_amdgcn_mfma_f32_16x16x32_bf16(af[ti], bfr[tj], acc[0][ti][tj], 0, 0, 0);
      }
      {
        bf16x8 bfr[4];
#pragma unroll
        for (int t = 0; t < 4; ++t)
          bfr[t] = *(const bf16x8*)(&sBk[cur][0] + (wn + t * 16 + col) * 64 + xo);
#pragma unroll
        for (int ti = 0; ti < 2; ++ti)
#pragma unroll
          for (int tj = 0; tj < 4; ++tj)
            acc[1][ti][tj] = __builtin_amdgcn_mfma_f32_16x16x32_bf16(af[ti], bfr[tj], acc[1][ti][tj], 0, 0, 0);
      }
      {
        bf16x8 bfr[4];
#pragma unroll
        for (int t = 0; t < 4; ++t)
          bfr[t] = *(const bf16x8*)(&sBv[cur][0] + (wn + t * 16 + col) * 64 + xo);
#pragma unroll
        for (int ti = 0; ti < 2; ++ti)
#pragma unroll
          for (int tj = 0; tj < 4; ++tj)
            acc[2][ti][tj] = __builtin_amdgcn_mfma_f32_16x16x32_bf16(af[ti], bfr[tj], acc[2][ti][tj], 0, 0, 0);
      }
    }
    __builtin_amdgcn_sched_barrier(0);
    __builtin_amdgcn_s_barrier();          // all waves done reading cur before restage
  }

#pragma unroll
  for (int z = 0; z < 3; ++z) {
    const float* bias = (z == 0) ? bq : (z == 1) ? bk : bv;
    unsigned short* Phi = (z == 0) ? Qhi : (z == 1) ? Khi : Vthi;
    unsigned short* Plo = (z == 0) ? Qlo : (z == 1) ? Klo : Vtlo;
    const float pre = (z == 0) ? 0.125f : 1.0f;
#pragma unroll
    for (int ti = 0; ti < 2; ++ti) {
#pragma unroll
      for (int tj = 0; tj < 4; ++tj) {
        int n = bn + wn + tj * 16 + col;
        float bv_ = bias[n];
        if (z != 2) {
#pragma unroll
          for (int i = 0; i < 4; ++i) {
            int m = bm + wm + ti * 16 + quad * 4 + i;
            float v = (acc[z][ti][tj][i] + bv_) * pre;
            unsigned short h = f32_to_bf16_rne(v);
            float hf = __uint_as_float((unsigned)h << 16);
            Phi[(size_t)m * 1024 + n] = h;
            Plo[(size_t)m * 1024 + n] = f32_to_bf16_rne(v - hf);
          }
        } else {
          int m0 = bm + wm + ti * 16 + quad * 4;  // 4 consecutive s in one batch
          u16x4 h4, l4;
#pragma unroll
          for (int i = 0; i < 4; ++i) {
            float v = acc[z][ti][tj][i] + bv_;
            unsigned short h = f32_to_bf16_rne(v);
            float hf = __uint_as_float((unsigned)h << 16);
            h4[i] = h;
            l4[i] = f32_to_bf16_rne(v - hf);
          }
          size_t idx = ((size_t)((m0 >> 10) * 1024 + n)) * 1024 + (m0 & 1023);
          *(u16x4*)(Phi + idx) = h4;
          *(u16x4*)(Plo + idx) = l4;
        }
      }
    }
  }
}

// ---------------- O-projection GEMM: 64x128 tile, double-buffered (R6) --------
// grid (8,64) = 512 WGs, 2 WG/CU (8 waves/CU). LDS 48KB. vmcnt(6) pipeline,
// XCD-bijective swizzle.

__global__ __launch_bounds__(256)
void gemm_o(const unsigned short* __restrict__ A, const unsigned short* __restrict__ Bw,
            const float* __restrict__ bias, float* __restrict__ C) {
  __shared__ unsigned short sA[2][64 * 64];
  __shared__ unsigned short sB[2][128 * 64];
  const int tid = threadIdx.x;
  const int w = tid >> 6, ln = tid & 63;
  const int fid = blockIdx.y * 8 + blockIdx.x;
  const int xcd = fid & 7, sq = fid >> 3;
  const int bm = (xcd * 8 + (sq & 7)) * 64, bn = (sq >> 3) * 128;
  const int wr = (w >> 1) * 32, wc = (w & 1) * 64;
  const int quad = ln >> 4, col = ln & 15;

  f32x4 acc[2][4];
  f32x4 zero = {0.0f, 0.0f, 0.0f, 0.0f};
#pragma unroll
  for (int i = 0; i < 2; ++i)
#pragma unroll
    for (int j = 0; j < 4; ++j) acc[i][j] = zero;

  const int srow = ln >> 3;
  const int gsw  = (ln & 7) ^ srow;
  const int xo0 = (quad ^ (ln & 7)) * 8;
  const int xo1 = ((quad ^ 4) ^ (ln & 7)) * 8;

  auto STAGE = [&](int bb, int k0) {
#pragma unroll
    for (int qa = 0; qa < 2; ++qa) {
      int row = w * 16 + qa * 8 + srow;
      __builtin_amdgcn_global_load_lds(
          (const __attribute__((address_space(1))) unsigned int*)(A + (size_t)(bm + row) * 1024 + k0 + gsw * 8),
          (__attribute__((address_space(3))) unsigned int*)(&sA[bb][0] + (w * 16 + qa * 8) * 64),
          16, 0, 0);
    }
#pragma unroll
    for (int qb = 0; qb < 4; ++qb) {
      int row = w * 32 + qb * 8 + srow;
      __builtin_amdgcn_global_load_lds(
          (const __attribute__((address_space(1))) unsigned int*)(Bw + (size_t)(bn + row) * 1024 + k0 + gsw * 8),
          (__attribute__((address_space(3))) unsigned int*)(&sB[bb][0] + (w * 32 + qb * 8) * 64),
          16, 0, 0);
    }
  };

  STAGE(0, 0);
#pragma unroll 1
  for (int k0 = 0; k0 < 1024; k0 += 64) {
    const int cur = (k0 >> 6) & 1;
    if (k0 < 960) {
      STAGE(cur ^ 1, k0 + 64);
      asm volatile("s_waitcnt vmcnt(6)" ::: "memory");
    } else {
      asm volatile("s_waitcnt vmcnt(0)" ::: "memory");
    }
    __builtin_amdgcn_s_barrier();
    __builtin_amdgcn_sched_barrier(0);

    const unsigned short* pA = &sA[cur][0];
    const unsigned short* pB = &sB[cur][0];
#pragma unroll
    for (int ks = 0; ks < 2; ++ks) {
      const int xo = ks ? xo1 : xo0;
      bf16x8 af[2], bfr[4];
#pragma unroll
      for (int t = 0; t < 2; ++t)
        af[t] = *(const bf16x8*)(pA + (wr + t * 16 + col) * 64 + xo);
#pragma unroll
      for (int t = 0; t < 4; ++t)
        bfr[t] = *(const bf16x8*)(pB + (wc + t * 16 + col) * 64 + xo);
#pragma unroll
      for (int ti = 0; ti < 2; ++ti)
#pragma unroll
        for (int tj = 0; tj < 4; ++tj)
          acc[ti][tj] = __builtin_amdgcn_mfma_f32_16x16x32_bf16(af[ti], bfr[tj], acc[ti][tj], 0, 0, 0);
    }
    __builtin_amdgcn_sched_barrier(0);
    __builtin_amdgcn_s_barrier();
  }

#pragma unroll
  for (int ti = 0; ti < 2; ++ti) {
#pragma unroll
    for (int tj = 0; tj < 4; ++tj) {
      int n = bn + wc + tj * 16 + col;
      float bv_ = bias[n];
#pragma unroll
      for (int i = 0; i < 4; ++i) {
        int m = bm + wr + ti * 16 + quad * 4 + i;
        C[(size_t)m * 1024 + n] = acc[ti][tj][i] + bv_;
      }
    }
  }
}

// ---------------- MFMA flash attention, skewed QK/PV pipeline (R7/R8) ----------
// grid (16,64), XCD-swizzled. KT=64, 4 waves x 16 q-rows. LDS 32KB (4 WGs/CU).
// S^T = K·Q^T => lane owns q=w*16+col; P register-resident via permlane swaps.
// Phase t: QK(t) + PV(t-1) MFMA back-to-back, then softmax(t) VALU (overlaps
// PV in the pipe). o-sequence {o += P(t-1)V(t-1); o *= alpha(t)} is bit-equal
// to the serial form. V staging lags K by one tile. Defer-max rescale.

__global__ __launch_bounds__(256, 4)
void attn_kernel(const unsigned short* __restrict__ Qhi, const unsigned short* __restrict__ Qlo,
                 const unsigned short* __restrict__ Khi, const unsigned short* __restrict__ Klo,
                 const unsigned short* __restrict__ Vthi, const unsigned short* __restrict__ Vtlo,
                 unsigned short* __restrict__ ctxq) {
  const int tid = threadIdx.x;
  const int id = blockIdx.y * 16 + blockIdx.x;
  const int qt = (id >> 3) & 15;
  const int bh = ((id >> 7) << 3) | (id & 7);
  const int b = bh >> 4, h = bh & 15;
  const int w = tid >> 6, ln = tid & 63, quad = ln >> 4, col = ln & 15;

  __shared__ __align__(16) short sK[16384];  // Khi@0, Klo@4096, Vthi@8192, Vtlo@12288 (shorts)

  // Q fragments (B-operand): lane holds Q[q=w*16+col][d=quad*8+e (+32 for ks=1)]
  bf16x8 qh[2], ql[2];
  {
    const size_t qoff = (size_t)(b * 1024 + qt * 64 + w * 16 + col) * 1024 + h * 64 + quad * 8;
    qh[0] = *(const bf16x8*)(Qhi + qoff);
    qh[1] = *(const bf16x8*)(Qhi + qoff + 32);
    ql[0] = *(const bf16x8*)(Qlo + qoff);
    ql[1] = *(const bf16x8*)(Qlo + qoff + 32);
  }

  // staging: wave w stages plane w into region w; K waves lead, V waves lag 1 tile
  const unsigned short* gplane = (w == 0) ? Khi : (w == 1) ? Klo : (w == 2) ? Vthi : Vtlo;
  short* splane = sK + w * 4096;
  const int r8 = ln >> 3;
  const int ch = (ln & 7) ^ r8;
  const unsigned short* bp = (w < 2)
      ? gplane + (size_t)(b * 1024 + r8) * 1024 + h * 64 + ch * 8
      : gplane + (size_t)(b * 1024 + h * 64 + r8) * 1024 + ch * 8;
  const int ktstep = (w < 2) ? 65536 : 64;

  const int xo0 = (quad ^ (col & 7)) * 8;
  const int xo1 = ((quad + 4) ^ (col & 7)) * 8;

  f32x4 o[4];
  f32x4 zero = {0.0f, 0.0f, 0.0f, 0.0f};
#pragma unroll
  for (int t = 0; t < 4; ++t) o[t] = zero;
  float m_ = -3.0e38f, l_ = 0.0f;
  bf16x8 pah[2], pal[2];  // P(t) fragments, carried across the phase boundary

  const float LOG2E = 1.44269504088896340736f;

  auto STAGE = [&]() {
#pragma unroll
    for (int g = 0; g < 8; ++g) {
      __builtin_amdgcn_global_load_lds(
          (const __attribute__((address_space(1))) unsigned int*)(bp + g * 8192),
          (__attribute__((address_space(3))) unsigned int*)(splane + g * 512),
          16, 0, 0);
    }
  };

#pragma unroll 1
  for (int kt = 0; kt < 16; ++kt) {
    __syncthreads();  // prior phase's fragment reads complete before restaging
    if (w < 2 || kt > 0) {  // K waves stage tile kt; V waves stage tile kt-1
      STAGE();
      bp += ktstep;
    }
    __syncthreads();  // staging visible (compiler drains vmcnt before barrier)

    // QK(kt): S^T = (Khi+Klo)·(Qhi+Qlo)^T, 3 cross terms (Q pre-scaled by 1/8)
    f32x4 s[4];
#pragma unroll
    for (int t = 0; t < 4; ++t) s[t] = zero;
#pragma unroll
    for (int t = 0; t < 4; ++t) {
      const int rb = (t * 16 + col) * 64;
#pragma unroll
      for (int ks = 0; ks < 2; ++ks) {
        const int xo = ks ? xo1 : xo0;
        bf16x8 kh = *(const bf16x8*)(sK +        rb + xo);
        bf16x8 kl = *(const bf16x8*)(sK + 4096 + rb + xo);
        s[t] = __builtin_amdgcn_mfma_f32_16x16x32_bf16(kh, ql[ks], s[t], 0, 0, 0);
        s[t] = __builtin_amdgcn_mfma_f32_16x16x32_bf16(kl, qh[ks], s[t], 0, 0, 0);
        s[t] = __builtin_amdgcn_mfma_f32_16x16x32_bf16(kh, qh[ks], s[t], 0, 0, 0);
      }
    }

    // PV(kt-1): O^T += (Vhi+Vlo)·(Phi+Plo)^T — independent of s, overlaps softmax
    if (kt > 0) {
#pragma unroll
      for (int nt = 0; nt < 4; ++nt) {
        const int rb = (nt * 16 + col) * 64;
#pragma unroll
        for (int ks = 0; ks < 2; ++ks) {
          const int xo = ks ? xo1 : xo0;
          bf16x8 vh = *(const bf16x8*)(sK +  8192 + rb + xo);
          bf16x8 vl = *(const bf16x8*)(sK + 12288 + rb + xo);
          o[nt] = __builtin_amdgcn_mfma_f32_16x16x32_bf16(vh, pal[ks], o[nt], 0, 0, 0);
          o[nt] = __builtin_amdgcn_mfma_f32_16x16x32_bf16(vl, pah[ks], o[nt], 0, 0, 0);
          o[nt] = __builtin_amdgcn_mfma_f32_16x16x32_bf16(vh, pah[ks], o[nt], 0, 0, 0);
        }
      }
    }

    // ---- softmax(kt): MX quantize scores, lane-local row ----
    float mx0 = fmaxf(fmaxf(fmaxf(s[0][0], s[0][1]), fmaxf(s[0][2], s[0][3])),
                      fmaxf(fmaxf(s[1][0], s[1][1]), fmaxf(s[1][2], s[1][3])));
    float mn0 = fminf(fminf(fminf(s[0][0], s[0][1]), fminf(s[0][2], s[0][3])),
                      fminf(fminf(s[1][0], s[1][1]), fminf(s[1][2], s[1][3])));
    float mx1 = fmaxf(fmaxf(fmaxf(s[2][0], s[2][1]), fmaxf(s[2][2], s[2][3])),
                      fmaxf(fmaxf(s[3][0], s[3][1]), fmaxf(s[3][2], s[3][3])));
    float mn1 = fminf(fminf(fminf(s[2][0], s[2][1]), fminf(s[2][2], s[2][3])),
                      fminf(fminf(s[3][0], s[3][1]), fminf(s[3][2], s[3][3])));
    mx0 = quad_red_max(mx0); mn0 = quad_red_min(mn0);
    mx1 = quad_red_max(mx1); mn1 = quad_red_min(mn1);

    float sc0, iv0, sc1, iv1;
    mx_scale_bits(fmaxf(mx0, -mn0), sc0, iv0);
    mx_scale_bits(fmaxf(mx1, -mn1), sc1, iv1);
    float scl0 = sc0 * LOG2E, scl1 = sc1 * LOG2E;  // fold dequant + log2e
    // quantize to e4m3 units; dequant folded into exp2 fma below
#pragma unroll
    for (int t = 0; t < 4; ++t) {
      float iv = (t < 2) ? iv0 : iv1;
      float q0 = s[t][0] * iv, q1 = s[t][1] * iv;
      qdq2(q0, q1);
      float q2 = s[t][2] * iv, q3 = s[t][3] * iv;
      qdq2(q2, q3);
      s[t][0] = q0; s[t][1] = q1; s[t][2] = q2; s[t][3] = q3;
    }
    float d0 = mx0 * iv0, d1 = mx1 * iv1;
    qdq2(d0, d1);
    float mt = fmaxf(d0 * scl0, d1 * scl1);  // row-max of quantized (qdq monotone)

    // online softmax (log2 domain), defer-max: rescale only when max grew > 4.
    // NOTE: rescale reads o AFTER PV(kt-1) accumulated — exact ordering.
    if (__any(mt > m_ + 4.0f)) {
      float mnew  = fmaxf(m_, mt);
      float alpha = __builtin_amdgcn_exp2f(m_ - mnew);
      m_ = mnew;
      l_ *= alpha;
#pragma unroll
      for (int nt = 0; nt < 4; ++nt)
#pragma unroll
        for (int i = 0; i < 4; ++i) o[nt][i] *= alpha;
    }
#pragma unroll
    for (int t = 0; t < 4; ++t) {
      float scl = (t < 2) ? scl0 : scl1;
      float p0 = __builtin_amdgcn_exp2f(__builtin_fmaf(s[t][0], scl, -m_));
      float p1 = __builtin_amdgcn_exp2f(__builtin_fmaf(s[t][1], scl, -m_));
      float p2 = __builtin_amdgcn_exp2f(__builtin_fmaf(s[t][2], scl, -m_));
      float p3 = __builtin_amdgcn_exp2f(__builtin_fmaf(s[t][3], scl, -m_));
      s[t][0] = p0; s[t][1] = p1; s[t][2] = p2; s[t][3] = p3;
      l_ += (p0 + p1) + (p2 + p3);
    }

    // ---- pack P(kt) -> bf16 hi/lo pairs; permlane redistribute to B-frags ----
    // (overwrites pah/pal AFTER PV(kt-1) consumed them)
    unsigned Wh[4][2], Wl[4][2];
#pragma unroll
    for (int t = 0; t < 4; ++t) {
#pragma unroll
      for (int u = 0; u < 2; ++u) {
        float a = s[t][2 * u], c = s[t][2 * u + 1];
        __hip_bfloat162 h2 = __float22bfloat162_rn(make_float2(a, c));
        unsigned uh = *(unsigned*)&h2;                 // lo16=bf(a), hi16=bf(c)
        float af = __uint_as_float(uh << 16);
        float cf = __uint_as_float(uh & 0xffff0000u);
        __hip_bfloat162 l2 = __float22bfloat162_rn(make_float2(a - af, c - cf));
        Wh[t][u] = uh;
        Wl[t][u] = *(unsigned*)&l2;
      }
    }
#pragma unroll
    for (int ks = 0; ks < 2; ++ks) {
      auto a0  = __builtin_amdgcn_permlane32_swap(Wh[2 * ks][0], Wh[2 * ks + 1][0], false, false);
      auto j02 = __builtin_amdgcn_permlane16_swap(a0[0], a0[1], false, false);
      auto a1  = __builtin_amdgcn_permlane32_swap(Wh[2 * ks][1], Wh[2 * ks + 1][1], false, false);
      auto j13 = __builtin_amdgcn_permlane16_swap(a1[0], a1[1], false, false);
      u32x4 hw; hw[0] = j02[0]; hw[1] = j13[0]; hw[2] = j02[1]; hw[3] = j13[1];
      pah[ks] = __builtin_bit_cast(bf16x8, hw);
      auto b0  = __builtin_amdgcn_permlane32_swap(Wl[2 * ks][0], Wl[2 * ks + 1][0], false, false);
      auto k02 = __builtin_amdgcn_permlane16_swap(b0[0], b0[1], false, false);
      auto b1  = __builtin_amdgcn_permlane32_swap(Wl[2 * ks][1], Wl[2 * ks + 1][1], false, false);
      auto k13 = __builtin_amdgcn_permlane16_swap(b1[0], b1[1], false, false);
      u32x4 lw; lw[0] = k02[0]; lw[1] = k13[0]; lw[2] = k02[1]; lw[3] = k13[1];
      pal[ks] = __builtin_bit_cast(bf16x8, lw);
    }
  }

  // drain: stage V(15), then PV(15)
  __syncthreads();
  if (w >= 2) STAGE();
  __syncthreads();
#pragma unroll
  for (int nt = 0; nt < 4; ++nt) {
    const int rb = (nt * 16 + col) * 64;
#pragma unroll
    for (int ks = 0; ks < 2; ++ks) {
      const int xo = ks ? xo1 : xo0;
      bf16x8 vh = *(const bf16x8*)(sK +  8192 + rb + xo);
      bf16x8 vl = *(const bf16x8*)(sK + 12288 + rb + xo);
      o[nt] = __builtin_amdgcn_mfma_f32_16x16x32_bf16(vh, pal[ks], o[nt], 0, 0, 0);
      o[nt] = __builtin_amdgcn_mfma_f32_16x16x32_bf16(vl, pah[ks], o[nt], 0, 0, 0);
      o[nt] = __builtin_amdgcn_mfma_f32_16x16x32_bf16(vh, pah[ks], o[nt], 0, 0, 0);
    }
  }

  // normalize + fused ctx MX quant (blocks of 32 along E = nt pairs) -> bf16
  float linv = 1.0f / quad_red_sum(l_);
#pragma unroll
  for (int nt = 0; nt < 4; ++nt)
#pragma unroll
    for (int i = 0; i < 4; ++i) o[nt][i] *= linv;

  float am0 = 0.0f, am1 = 0.0f;
#pragma unroll
  for (int i = 0; i < 4; ++i) {
    am0 = fmaxf(am0, fmaxf(__builtin_fabsf(o[0][i]), __builtin_fabsf(o[1][i])));
    am1 = fmaxf(am1, fmaxf(__builtin_fabsf(o[2][i]), __builtin_fabsf(o[3][i])));
  }
  am0 = quad_red_max(am0);
  am1 = quad_red_max(am1);
  float sc0, iv0, sc1, iv1;
  mx_scale_bits(am0, sc0, iv0);
  mx_scale_bits(am1, sc1, iv1);

  const int tok = b * 1024 + qt * 64 + w * 16 + col;
  const size_t base = (size_t)tok * 1024 + h * 64 + quad * 4;
#pragma unroll
  for (int nt = 0; nt < 4; ++nt) {
    float iv = (nt < 2) ? iv0 : iv1;
    float sc = (nt < 2) ? sc0 : sc1;
    float q0 = o[nt][0] * iv, q1 = o[nt][1] * iv;
    qdq2(q0, q1);
    float q2 = o[nt][2] * iv, q3 = o[nt][3] * iv;
    qdq2(q2, q3);
    u16x4 h4;
    h4[0] = (unsigned short)(__float_as_uint(q0 * sc) >> 16);  // exact bf16
    h4[1] = (unsigned short)(__float_as_uint(q1 * sc) >> 16);
    h4[2] = (unsigned short)(__float_as_uint(q2 * sc) >> 16);
    h4[3] = (unsigned short)(__float_as_uint(q3 * sc) >> 16);
    *(u16x4*)(ctxq + base + nt * 16) = h4;
  }
}

// ---------------- launch ----------------

extern "C" void kernel_launch(void* const* d_in, const int* in_sizes, int n_in,
                              void* d_out, int out_size, void* d_ws, size_t ws_size,
                              hipStream_t stream) {
  (void)in_sizes; (void)n_in; (void)out_size; (void)ws_size;
  const float* x  = (const float*)d_in[0];
  const float* Wq = (const float*)d_in[1];
  const float* bq = (const float*)d_in[2];
  const float* Wk = (const float*)d_in[3];
  const float* bk = (const float*)d_in[4];
  const float* Wv = (const float*)d_in[5];
  const float* bv = (const float*)d_in[6];
  const float* Wo = (const float*)d_in[7];
  const float* bo = (const float*)d_in[8];

  char* wsb = (char*)d_ws;
  const size_t MB = (size_t)1 << 20;
  unsigned short* XQb   = (unsigned short*)(wsb + 0);
  unsigned short* WQb   = (unsigned short*)(wsb + 8 * MB);
  unsigned short* WKb   = (unsigned short*)(wsb + 10 * MB);
  unsigned short* WVb   = (unsigned short*)(wsb + 12 * MB);
  unsigned short* WOb   = (unsigned short*)(wsb + 14 * MB);
  unsigned short* Qhi   = (unsigned short*)(wsb + 16 * MB);
  unsigned short* Qlo   = (unsigned short*)(wsb + 24 * MB);
  unsigned short* Khi   = (unsigned short*)(wsb + 32 * MB);
  unsigned short* Klo   = (unsigned short*)(wsb + 40 * MB);
  unsigned short* Vthi  = (unsigned short*)(wsb + 48 * MB);
  unsigned short* Vtlo  = (unsigned short*)(wsb + 56 * MB);
  unsigned short* CTXQb = XQb;  // reuse: XQ dead after V projection

  mxq_all<<<1024, 256, 0, stream>>>(x, Wq, Wk, Wv, Wo, XQb, WQb, WKb, WVb, WOb);

  dim3 qkvgrid(8, 32);  // 256 WGs = exactly 1/CU (z-merged)
  gemm_qkv<<<qkvgrid, 512, 0, stream>>>(XQb, WQb, WKb, WVb, bq, bk, bv,
                                        Qhi, Qlo, Khi, Klo, Vthi, Vtlo);

  dim3 agrid(16, 64);  // 1024 WGs, XCD-swizzled inside the kernel
  attn_kernel<<<agrid, 256, 0, stream>>>(Qhi, Qlo, Khi, Klo, Vthi, Vtlo, CTXQb);

  dim3 ogrid(8, 64);  // 512 WGs, XCD-swizzled inside the kernel
  gemm_o<<<ogrid, 256, 0, stream>>>(CTXQb, WOb, bo, (float*)d_out);
}